// Round 1
// baseline (778.145 us; speedup 1.0000x reference)
//
#include <hip/hip_runtime.h>
#include <math.h>

#define N_NODES 50000
#define N_EDGES 600000
#define D_IN    128
#define D_HID   256
#define D_OUT   128

// ---------------------------------------------------------------------------
// Setup kernels: softplus edge weights, degree, dinv, CSR build
// ---------------------------------------------------------------------------

__global__ void k_edge_prep(const int* __restrict__ src, const int* __restrict__ dst,
                            const float* __restrict__ w, float* __restrict__ ew,
                            float* __restrict__ deg, int* __restrict__ cnt) {
    int e = blockIdx.x * blockDim.x + threadIdx.x;
    if (e >= N_EDGES) return;
    float x = w[e];
    // numerically stable softplus
    float sp = fmaxf(x, 0.f) + log1pf(expf(-fabsf(x)));
    ew[e] = sp;
    int d = dst[e];
    atomicAdd(&deg[d], sp);
    atomicAdd(&cnt[d], 1);
    (void)src;
}

__global__ void k_dinv(float* __restrict__ deg) {
    int n = blockIdx.x * blockDim.x + threadIdx.x;
    if (n >= N_NODES) return;
    // +1.0 for the self-loop weight; deg >= 1 so rsqrt is always valid
    deg[n] = rsqrtf(deg[n] + 1.0f);
}

// single-block exclusive scan of cnt[0..N) -> rowptr[0..N]
__global__ void k_scan(const int* __restrict__ cnt, int* __restrict__ rowptr) {
    __shared__ int part[1024];
    const int T = 1024;
    int t = threadIdx.x;
    const int chunk = (N_NODES + T - 1) / T;  // 49
    int begin = t * chunk;
    int end = begin + chunk; if (end > N_NODES) end = N_NODES;
    int s = 0;
    for (int i = begin; i < end && i >= begin; i++) s += cnt[i];
    part[t] = s;
    __syncthreads();
    // Hillis-Steele inclusive scan
    for (int off = 1; off < T; off <<= 1) {
        int v = (t >= off) ? part[t - off] : 0;
        __syncthreads();
        part[t] += v;
        __syncthreads();
    }
    int run = (t == 0) ? 0 : part[t - 1];  // exclusive prefix
    for (int i = begin; i < end && i >= begin; i++) {
        rowptr[i] = run;
        run += cnt[i];
    }
    if (end == N_NODES) rowptr[N_NODES] = run;  // all such threads write same total
}

__global__ void k_fill(const int* __restrict__ src, const int* __restrict__ dst,
                       const float* __restrict__ ew, const float* __restrict__ dinv,
                       const int* __restrict__ rowptr, int* __restrict__ fill,
                       int* __restrict__ col, float* __restrict__ nrm) {
    int e = blockIdx.x * blockDim.x + threadIdx.x;
    if (e >= N_EDGES) return;
    int d = dst[e];
    int s = src[e];
    int pos = rowptr[d] + atomicAdd(&fill[d], 1);
    col[pos] = s;
    nrm[pos] = dinv[s] * ew[e] * dinv[d];
}

// ---------------------------------------------------------------------------
// Aggregation: out[n,:] = sum_{e: dst=n} nrm[e]*in[col[e],:] + dinv[n]^2*in[n,:] (+bias)
// One wave (64 lanes) per node. D=128 -> float2/lane, D=256 -> float4/lane.
// ---------------------------------------------------------------------------

template <int D, bool BIAS>
__global__ __launch_bounds__(256) void k_agg(const float* __restrict__ in,
                                             const int* __restrict__ rowptr,
                                             const int* __restrict__ col,
                                             const float* __restrict__ nrm,
                                             const float* __restrict__ dinv,
                                             const float* __restrict__ bias,
                                             float* __restrict__ out) {
    int node = blockIdx.x * 4 + (threadIdx.x >> 6);
    int lane = threadIdx.x & 63;
    if (node >= N_NODES) return;
    float dn = dinv[node];
    float dd = dn * dn;
    int beg = rowptr[node], end = rowptr[node + 1];

    if (D == 256) {
        const float4* selfr = reinterpret_cast<const float4*>(in + (size_t)node * D) + lane;
        float4 sv = *selfr;
        float ax = dd * sv.x, ay = dd * sv.y, az = dd * sv.z, aw = dd * sv.w;
        for (int p = beg; p < end; p++) {
            int s = col[p];
            float wv = nrm[p];
            const float4* r = reinterpret_cast<const float4*>(in + (size_t)s * D) + lane;
            float4 rv = *r;
            ax += wv * rv.x; ay += wv * rv.y; az += wv * rv.z; aw += wv * rv.w;
        }
        if (BIAS) {
            const float4* bv = reinterpret_cast<const float4*>(bias) + lane;
            float4 b = *bv;
            ax += b.x; ay += b.y; az += b.z; aw += b.w;
        }
        float4* o = reinterpret_cast<float4*>(out + (size_t)node * D) + lane;
        float4 res; res.x = ax; res.y = ay; res.z = az; res.w = aw;
        *o = res;
    } else {  // D == 128
        const float2* selfr = reinterpret_cast<const float2*>(in + (size_t)node * D) + lane;
        float2 sv = *selfr;
        float ax = dd * sv.x, ay = dd * sv.y;
        for (int p = beg; p < end; p++) {
            int s = col[p];
            float wv = nrm[p];
            const float2* r = reinterpret_cast<const float2*>(in + (size_t)s * D) + lane;
            float2 rv = *r;
            ax += wv * rv.x; ay += wv * rv.y;
        }
        if (BIAS) {
            const float2* bv = reinterpret_cast<const float2*>(bias) + lane;
            float2 b = *bv;
            ax += b.x; ay += b.y;
        }
        float2* o = reinterpret_cast<float2*>(out + (size_t)node * D) + lane;
        float2 res; res.x = ax; res.y = ay;
        *o = res;
    }
}

// ---------------------------------------------------------------------------
// f32 GEMM: C[M,N] = A[M,K] @ B[K,N] (+bias, +relu). 64x64 tile, 256 threads,
// 4x4 micro-tile per thread. As padded to 65 to avoid 16-way bank conflict.
// ---------------------------------------------------------------------------

template <bool BIAS, bool RELU>
__global__ __launch_bounds__(256) void k_gemm(const float* __restrict__ A,
                                              const float* __restrict__ B,
                                              const float* __restrict__ bias,
                                              float* __restrict__ C,
                                              int M, int K, int N) {
    __shared__ float As[16][65];
    __shared__ float Bs[16][64];
    int tid = threadIdx.x;
    int tx = tid & 15;       // col group
    int ty = tid >> 4;       // row group
    int bm = blockIdx.y * 64;
    int bn = blockIdx.x * 64;

    float acc[4][4];
    #pragma unroll
    for (int i = 0; i < 4; i++)
        #pragma unroll
        for (int j = 0; j < 4; j++) acc[i][j] = 0.f;

    for (int k0 = 0; k0 < K; k0 += 16) {
        {   // load A tile: As[k][m]
            int k = tid & 15;
            int m0 = tid >> 4;
            #pragma unroll
            for (int i = 0; i < 4; i++) {
                int m = m0 + i * 16;
                int gr = bm + m;
                As[k][m] = (gr < M) ? A[(size_t)gr * K + k0 + k] : 0.f;
            }
        }
        {   // load B tile: Bs[kk][n]
            int n = tid & 63;
            int kk0 = tid >> 6;
            #pragma unroll
            for (int i = 0; i < 4; i++) {
                int kk = kk0 + i * 4;
                Bs[kk][n] = B[(size_t)(k0 + kk) * N + bn + n];
            }
        }
        __syncthreads();
        #pragma unroll
        for (int kk = 0; kk < 16; kk++) {
            float a[4], b[4];
            #pragma unroll
            for (int i = 0; i < 4; i++) a[i] = As[kk][ty + i * 16];
            #pragma unroll
            for (int j = 0; j < 4; j++) b[j] = Bs[kk][tx + j * 16];
            #pragma unroll
            for (int i = 0; i < 4; i++)
                #pragma unroll
                for (int j = 0; j < 4; j++)
                    acc[i][j] += a[i] * b[j];
        }
        __syncthreads();
    }

    #pragma unroll
    for (int i = 0; i < 4; i++) {
        int r = bm + ty + i * 16;
        if (r < M) {
            #pragma unroll
            for (int j = 0; j < 4; j++) {
                int c = bn + tx + j * 16;
                float v = acc[i][j];
                if (BIAS) v += bias[c];
                if (RELU) v = fmaxf(v, 0.f);
                C[(size_t)r * N + c] = v;
            }
        }
    }
}

// ---------------------------------------------------------------------------
// launch
// ---------------------------------------------------------------------------

extern "C" void kernel_launch(void* const* d_in, const int* in_sizes, int n_in,
                              void* d_out, int out_size, void* d_ws, size_t ws_size,
                              hipStream_t stream) {
    const float* x   = (const float*)d_in[0];
    const int*   ei  = (const int*)d_in[1];   // [2, E] int32
    const float* wts = (const float*)d_in[2];
    const float* W1  = (const float*)d_in[3];
    const float* b1  = (const float*)d_in[4];
    const float* W2  = (const float*)d_in[5];
    const float* b2  = (const float*)d_in[6];
    const float* W3  = (const float*)d_in[7];
    const float* b3  = (const float*)d_in[8];
    float* out = (float*)d_out;
    const int* src = ei;
    const int* dst = ei + N_EDGES;

    // workspace layout (all 16B-aligned by construction)
    float* bufA   = (float*)d_ws;                         // [N,256] max
    float* bufB   = bufA + (size_t)N_NODES * D_HID;       // [N,256] max
    float* ew     = bufB + (size_t)N_NODES * D_HID;       // [E]
    float* deg    = ew + N_EDGES;                         // [N]  (becomes dinv)
    int*   cnt    = (int*)(deg + N_NODES);                // [N]
    int*   fill   = cnt + N_NODES;                        // [N]
    int*   rowptr = fill + N_NODES;                       // [N+1]
    int*   col    = rowptr + (N_NODES + 2);               // [E]
    float* nrm    = (float*)(col + N_EDGES);              // [E]

    // zero deg + cnt + fill (contiguous)
    hipMemsetAsync(deg, 0, sizeof(float) * N_NODES + sizeof(int) * 2 * N_NODES, stream);

    int ethreads = 256;
    int eblocks = (N_EDGES + ethreads - 1) / ethreads;
    k_edge_prep<<<eblocks, ethreads, 0, stream>>>(src, dst, wts, ew, deg, cnt);
    k_dinv<<<(N_NODES + 255) / 256, 256, 0, stream>>>(deg);
    k_scan<<<1, 1024, 0, stream>>>(cnt, rowptr);
    k_fill<<<eblocks, ethreads, 0, stream>>>(src, dst, ew, deg, rowptr, fill, col, nrm);

    int aggBlocks = (N_NODES + 3) / 4;  // 4 waves per 256-thread block

    // Layer 1: h1 = relu((A.x) @ W1 + b1)   -- aggregate at d=128 first
    k_agg<128, false><<<aggBlocks, 256, 0, stream>>>(x, rowptr, col, nrm, deg, nullptr, bufA);
    {
        dim3 g(D_HID / 64, (N_NODES + 63) / 64);
        k_gemm<true, true><<<g, 256, 0, stream>>>(bufA, W1, b1, bufB, N_NODES, D_IN, D_HID);
    }
    // Layer 2: h2 = relu((A.h1) @ W2 + b2)  -- aggregate at d=256
    k_agg<256, false><<<aggBlocks, 256, 0, stream>>>(bufB, rowptr, col, nrm, deg, nullptr, bufA);
    {
        dim3 g(D_HID / 64, (N_NODES + 63) / 64);
        k_gemm<true, true><<<g, 256, 0, stream>>>(bufA, W2, b2, bufB, N_NODES, D_HID, D_HID);
    }
    // Layer 3: out = A.(h2 @ W3) + b3       -- GEMM to 128 first, aggregate after
    {
        dim3 g(D_OUT / 64, (N_NODES + 63) / 64);
        k_gemm<false, false><<<g, 256, 0, stream>>>(bufB, W3, nullptr, bufA, N_NODES, D_HID, D_OUT);
    }
    k_agg<128, true><<<aggBlocks, 256, 0, stream>>>(bufA, rowptr, col, nrm, deg, b3, out);
}

// Round 2
// 657.218 us; speedup vs baseline: 1.1840x; 1.1840x over previous
//
#include <hip/hip_runtime.h>
#include <math.h>

#define N_NODES 50000
#define N_EDGES 600000
#define D_IN    128
#define D_HID   256
#define D_OUT   128

// ---------------------------------------------------------------------------
// Setup kernels: softplus edge weights, degree, dinv, CSR build
// ---------------------------------------------------------------------------

__global__ void k_edge_prep(const int* __restrict__ src, const int* __restrict__ dst,
                            const float* __restrict__ w, float* __restrict__ ew,
                            float* __restrict__ deg, int* __restrict__ cnt) {
    int e = blockIdx.x * blockDim.x + threadIdx.x;
    if (e >= N_EDGES) return;
    float x = w[e];
    float sp = fmaxf(x, 0.f) + log1pf(expf(-fabsf(x)));
    ew[e] = sp;
    int d = dst[e];
    atomicAdd(&deg[d], sp);
    atomicAdd(&cnt[d], 1);
    (void)src;
}

__global__ void k_dinv(float* __restrict__ deg) {
    int n = blockIdx.x * blockDim.x + threadIdx.x;
    if (n >= N_NODES) return;
    deg[n] = rsqrtf(deg[n] + 1.0f);  // +1 self-loop; deg >= 1
}

// single-block exclusive scan of cnt[0..N) -> rowptr[0..N]
__global__ void k_scan(const int* __restrict__ cnt, int* __restrict__ rowptr) {
    __shared__ int part[1024];
    const int T = 1024;
    int t = threadIdx.x;
    const int chunk = (N_NODES + T - 1) / T;
    int begin = t * chunk;
    int end = begin + chunk; if (end > N_NODES) end = N_NODES;
    int s = 0;
    for (int i = begin; i < end && i >= begin; i++) s += cnt[i];
    part[t] = s;
    __syncthreads();
    for (int off = 1; off < T; off <<= 1) {
        int v = (t >= off) ? part[t - off] : 0;
        __syncthreads();
        part[t] += v;
        __syncthreads();
    }
    int run = (t == 0) ? 0 : part[t - 1];
    for (int i = begin; i < end && i >= begin; i++) {
        rowptr[i] = run;
        run += cnt[i];
    }
    if (end == N_NODES) rowptr[N_NODES] = run;
}

__global__ void k_fill(const int* __restrict__ src, const int* __restrict__ dst,
                       const float* __restrict__ ew, const float* __restrict__ dinv,
                       const int* __restrict__ rowptr, int* __restrict__ fill,
                       int* __restrict__ col, float* __restrict__ nrm) {
    int e = blockIdx.x * blockDim.x + threadIdx.x;
    if (e >= N_EDGES) return;
    int d = dst[e];
    int s = src[e];
    int pos = rowptr[d] + atomicAdd(&fill[d], 1);
    col[pos] = s;
    nrm[pos] = dinv[s] * ew[e] * dinv[d];
}

// ---------------------------------------------------------------------------
// Aggregation: out[n,:] = sum_{e: dst=n} nrm[e]*in[col[e],:] + dinv[n]^2*in[n,:] (+bias)
// One wave per node; edge loop unrolled x2 for gather ILP.
// ---------------------------------------------------------------------------

template <int D, bool BIAS>
__global__ __launch_bounds__(256) void k_agg(const float* __restrict__ in,
                                             const int* __restrict__ rowptr,
                                             const int* __restrict__ col,
                                             const float* __restrict__ nrm,
                                             const float* __restrict__ dinv,
                                             const float* __restrict__ bias,
                                             float* __restrict__ out) {
    int node = blockIdx.x * 4 + (threadIdx.x >> 6);
    int lane = threadIdx.x & 63;
    if (node >= N_NODES) return;
    float dn = dinv[node];
    float dd = dn * dn;
    int beg = rowptr[node], end = rowptr[node + 1];

    if (D == 256) {
        const float4* selfr = reinterpret_cast<const float4*>(in + (size_t)node * D) + lane;
        float4 sv = *selfr;
        float ax = dd * sv.x, ay = dd * sv.y, az = dd * sv.z, aw = dd * sv.w;
        int p = beg;
        for (; p + 1 < end; p += 2) {
            int s0 = col[p], s1 = col[p + 1];
            float w0 = nrm[p], w1 = nrm[p + 1];
            float4 r0 = *(reinterpret_cast<const float4*>(in + (size_t)s0 * D) + lane);
            float4 r1 = *(reinterpret_cast<const float4*>(in + (size_t)s1 * D) + lane);
            ax += w0 * r0.x; ay += w0 * r0.y; az += w0 * r0.z; aw += w0 * r0.w;
            ax += w1 * r1.x; ay += w1 * r1.y; az += w1 * r1.z; aw += w1 * r1.w;
        }
        if (p < end) {
            int s0 = col[p];
            float w0 = nrm[p];
            float4 r0 = *(reinterpret_cast<const float4*>(in + (size_t)s0 * D) + lane);
            ax += w0 * r0.x; ay += w0 * r0.y; az += w0 * r0.z; aw += w0 * r0.w;
        }
        if (BIAS) {
            float4 b = *(reinterpret_cast<const float4*>(bias) + lane);
            ax += b.x; ay += b.y; az += b.z; aw += b.w;
        }
        float4 res; res.x = ax; res.y = ay; res.z = az; res.w = aw;
        *(reinterpret_cast<float4*>(out + (size_t)node * D) + lane) = res;
    } else {  // D == 128
        const float2* selfr = reinterpret_cast<const float2*>(in + (size_t)node * D) + lane;
        float2 sv = *selfr;
        float ax = dd * sv.x, ay = dd * sv.y;
        int p = beg;
        for (; p + 1 < end; p += 2) {
            int s0 = col[p], s1 = col[p + 1];
            float w0 = nrm[p], w1 = nrm[p + 1];
            float2 r0 = *(reinterpret_cast<const float2*>(in + (size_t)s0 * D) + lane);
            float2 r1 = *(reinterpret_cast<const float2*>(in + (size_t)s1 * D) + lane);
            ax += w0 * r0.x; ay += w0 * r0.y;
            ax += w1 * r1.x; ay += w1 * r1.y;
        }
        if (p < end) {
            int s0 = col[p];
            float w0 = nrm[p];
            float2 r0 = *(reinterpret_cast<const float2*>(in + (size_t)s0 * D) + lane);
            ax += w0 * r0.x; ay += w0 * r0.y;
        }
        if (BIAS) {
            float2 b = *(reinterpret_cast<const float2*>(bias) + lane);
            ax += b.x; ay += b.y;
        }
        float2 res; res.x = ax; res.y = ay;
        *(reinterpret_cast<float2*>(out + (size_t)node * D) + lane) = res;
    }
}

// ---------------------------------------------------------------------------
// f32 GEMM: C[M,N] = A[M,K] @ B[K,N] (+bias, +relu).
// 128x128 tile, 256 threads, 8x8 micro-tile, ds_read_b128 fragment loads.
// As k-major, row stride 132 floats (16B-aligned rows, <=2-way bank alias).
// Bs k-major, row stride 128 (float4 staging writes, conflict-free).
// Requires K%16==0, N%128==0.
// ---------------------------------------------------------------------------

#define BM 128
#define BN 128
#define BK 16
#define AS_LD 132

template <bool BIAS, bool RELU>
__global__ __launch_bounds__(256) void k_gemm(const float* __restrict__ A,
                                              const float* __restrict__ B,
                                              const float* __restrict__ bias,
                                              float* __restrict__ C,
                                              int M, int K, int N) {
    __shared__ float As[BK * AS_LD];
    __shared__ float Bs[BK * BN];

    int tid = threadIdx.x;
    int tx = tid & 15;       // 0..15 -> col groups
    int ty = tid >> 4;       // 0..15 -> row groups
    int bm = blockIdx.y * BM;
    int bn = blockIdx.x * BN;

    float acc[8][8];
    #pragma unroll
    for (int i = 0; i < 8; i++)
        #pragma unroll
        for (int j = 0; j < 8; j++) acc[i][j] = 0.f;

    for (int k0 = 0; k0 < K; k0 += BK) {
        // ---- stage A tile: As[k][m], 512 float4 loads (2/thread) ----
        #pragma unroll
        for (int q = 0; q < 2; q++) {
            int idx = tid + q * 256;          // 0..511
            int row = idx >> 2;               // 0..127
            int kc  = (idx & 3) * 4;          // 0,4,8,12
            int gr = bm + row;
            float4 v;
            if (gr < M) v = *reinterpret_cast<const float4*>(A + (size_t)gr * K + k0 + kc);
            else        v = make_float4(0.f, 0.f, 0.f, 0.f);
            As[(kc + 0) * AS_LD + row] = v.x;
            As[(kc + 1) * AS_LD + row] = v.y;
            As[(kc + 2) * AS_LD + row] = v.z;
            As[(kc + 3) * AS_LD + row] = v.w;
        }
        // ---- stage B tile: Bs[kk][n], float4 in & out ----
        #pragma unroll
        for (int q = 0; q < 2; q++) {
            int idx = tid + q * 256;          // 0..511
            int kk = idx >> 5;                // 0..15
            int nc = (idx & 31) * 4;          // 0..124
            float4 v = *reinterpret_cast<const float4*>(B + (size_t)(k0 + kk) * N + bn + nc);
            *reinterpret_cast<float4*>(&Bs[kk * BN + nc]) = v;
        }
        __syncthreads();

        #pragma unroll
        for (int kk = 0; kk < BK; kk++) {
            float4 a0 = *reinterpret_cast<const float4*>(&As[kk * AS_LD + ty * 4]);
            float4 a1 = *reinterpret_cast<const float4*>(&As[kk * AS_LD + ty * 4 + 64]);
            float4 b0 = *reinterpret_cast<const float4*>(&Bs[kk * BN + tx * 4]);
            float4 b1 = *reinterpret_cast<const float4*>(&Bs[kk * BN + tx * 4 + 64]);
            float a[8] = {a0.x, a0.y, a0.z, a0.w, a1.x, a1.y, a1.z, a1.w};
            float b[8] = {b0.x, b0.y, b0.z, b0.w, b1.x, b1.y, b1.z, b1.w};
            #pragma unroll
            for (int i = 0; i < 8; i++)
                #pragma unroll
                for (int j = 0; j < 8; j++)
                    acc[i][j] += a[i] * b[j];
        }
        __syncthreads();
    }

    // ---- epilogue: 8 rows x 2 float4 stores ----
    float4 bv0, bv1;
    if (BIAS) {
        bv0 = *reinterpret_cast<const float4*>(bias + bn + tx * 4);
        bv1 = *reinterpret_cast<const float4*>(bias + bn + tx * 4 + 64);
    }
    #pragma unroll
    for (int i = 0; i < 8; i++) {
        int r = bm + ty * 4 + (i & 3) + (i >> 2) * 64;
        if (r >= M) continue;
        float4 v0, v1;
        v0.x = acc[i][0]; v0.y = acc[i][1]; v0.z = acc[i][2]; v0.w = acc[i][3];
        v1.x = acc[i][4]; v1.y = acc[i][5]; v1.z = acc[i][6]; v1.w = acc[i][7];
        if (BIAS) {
            v0.x += bv0.x; v0.y += bv0.y; v0.z += bv0.z; v0.w += bv0.w;
            v1.x += bv1.x; v1.y += bv1.y; v1.z += bv1.z; v1.w += bv1.w;
        }
        if (RELU) {
            v0.x = fmaxf(v0.x, 0.f); v0.y = fmaxf(v0.y, 0.f);
            v0.z = fmaxf(v0.z, 0.f); v0.w = fmaxf(v0.w, 0.f);
            v1.x = fmaxf(v1.x, 0.f); v1.y = fmaxf(v1.y, 0.f);
            v1.z = fmaxf(v1.z, 0.f); v1.w = fmaxf(v1.w, 0.f);
        }
        *reinterpret_cast<float4*>(C + (size_t)r * N + bn + tx * 4) = v0;
        *reinterpret_cast<float4*>(C + (size_t)r * N + bn + tx * 4 + 64) = v1;
    }
}

// NOTE: acc[i][j]: i indexes rows {ty*4+0..3, ty*4+64..67}, j indexes cols
// {tx*4+0..3, tx*4+64..67}; a[]/b[] fragment order matches.

// ---------------------------------------------------------------------------
// launch
// ---------------------------------------------------------------------------

extern "C" void kernel_launch(void* const* d_in, const int* in_sizes, int n_in,
                              void* d_out, int out_size, void* d_ws, size_t ws_size,
                              hipStream_t stream) {
    const float* x   = (const float*)d_in[0];
    const int*   ei  = (const int*)d_in[1];   // [2, E] int32
    const float* wts = (const float*)d_in[2];
    const float* W1  = (const float*)d_in[3];
    const float* b1  = (const float*)d_in[4];
    const float* W2  = (const float*)d_in[5];
    const float* b2  = (const float*)d_in[6];
    const float* W3  = (const float*)d_in[7];
    const float* b3  = (const float*)d_in[8];
    float* out = (float*)d_out;
    const int* src = ei;
    const int* dst = ei + N_EDGES;

    float* bufA   = (float*)d_ws;                         // [N,256] max
    float* bufB   = bufA + (size_t)N_NODES * D_HID;       // [N,256] max
    float* ew     = bufB + (size_t)N_NODES * D_HID;       // [E]
    float* deg    = ew + N_EDGES;                         // [N] (becomes dinv)
    int*   cnt    = (int*)(deg + N_NODES);                // [N]
    int*   fill   = cnt + N_NODES;                        // [N]
    int*   rowptr = fill + N_NODES;                       // [N+1]
    int*   col    = rowptr + (N_NODES + 2);               // [E]
    float* nrm    = (float*)(col + N_EDGES);              // [E]

    hipMemsetAsync(deg, 0, sizeof(float) * N_NODES + sizeof(int) * 2 * N_NODES, stream);

    int ethreads = 256;
    int eblocks = (N_EDGES + ethreads - 1) / ethreads;
    k_edge_prep<<<eblocks, ethreads, 0, stream>>>(src, dst, wts, ew, deg, cnt);
    k_dinv<<<(N_NODES + 255) / 256, 256, 0, stream>>>(deg);
    k_scan<<<1, 1024, 0, stream>>>(cnt, rowptr);
    k_fill<<<eblocks, ethreads, 0, stream>>>(src, dst, ew, deg, rowptr, fill, col, nrm);

    int aggBlocks = (N_NODES + 3) / 4;
    int gy = (N_NODES + BM - 1) / BM;  // 391

    // Layer 1: h1 = relu((A.x) @ W1 + b1)   -- aggregate at d=128 first
    k_agg<128, false><<<aggBlocks, 256, 0, stream>>>(x, rowptr, col, nrm, deg, nullptr, bufA);
    {
        dim3 g(D_HID / BN, gy);
        k_gemm<true, true><<<g, 256, 0, stream>>>(bufA, W1, b1, bufB, N_NODES, D_IN, D_HID);
    }
    // Layer 2: h2 = relu((A.h1) @ W2 + b2)  -- aggregate at d=256
    k_agg<256, false><<<aggBlocks, 256, 0, stream>>>(bufB, rowptr, col, nrm, deg, nullptr, bufA);
    {
        dim3 g(D_HID / BN, gy);
        k_gemm<true, true><<<g, 256, 0, stream>>>(bufA, W2, b2, bufB, N_NODES, D_HID, D_HID);
    }
    // Layer 3: out = A.(h2 @ W3) + b3       -- GEMM to 128 first, aggregate after
    {
        dim3 g(D_OUT / BN, gy);
        k_gemm<false, false><<<g, 256, 0, stream>>>(bufB, W3, nullptr, bufA, N_NODES, D_HID, D_OUT);
    }
    k_agg<128, true><<<aggBlocks, 256, 0, stream>>>(bufA, rowptr, col, nrm, deg, b3, out);
}

// Round 4
// 577.829 us; speedup vs baseline: 1.3467x; 1.1374x over previous
//
#include <hip/hip_runtime.h>
#include <math.h>

#define N_NODES 50000
#define N_EDGES 600000
#define D_IN    128
#define D_HID   256
#define D_OUT   128

typedef unsigned short u16;
typedef __attribute__((ext_vector_type(8))) short bf16x8;
typedef __attribute__((ext_vector_type(4))) float f32x4;

__device__ __forceinline__ u16 f2bf(float x) {
    unsigned int u = __float_as_uint(x);
    unsigned int r = (u + 0x7fffu + ((u >> 16) & 1u)) >> 16;
    return (u16)r;
}
__device__ __forceinline__ float bf2f(u16 h) {
    return __uint_as_float(((unsigned int)h) << 16);
}

// ---------------------------------------------------------------------------
// Setup: softplus, degree, dinv, CSR
// ---------------------------------------------------------------------------

__global__ void k_edge_prep(const int* __restrict__ src, const int* __restrict__ dst,
                            const float* __restrict__ w, float* __restrict__ ew,
                            float* __restrict__ deg, int* __restrict__ cnt) {
    int e = blockIdx.x * blockDim.x + threadIdx.x;
    if (e >= N_EDGES) return;
    float x = w[e];
    float sp = fmaxf(x, 0.f) + log1pf(expf(-fabsf(x)));
    ew[e] = sp;
    int d = dst[e];
    atomicAdd(&deg[d], sp);
    atomicAdd(&cnt[d], 1);
    (void)src;
}

__global__ void k_dinv(float* __restrict__ deg) {
    int n = blockIdx.x * blockDim.x + threadIdx.x;
    if (n >= N_NODES) return;
    deg[n] = rsqrtf(deg[n] + 1.0f);
}

__global__ void k_scan(const int* __restrict__ cnt, int* __restrict__ rowptr) {
    __shared__ int part[1024];
    const int T = 1024;
    int t = threadIdx.x;
    const int chunk = (N_NODES + T - 1) / T;
    int begin = t * chunk;
    int end = begin + chunk; if (end > N_NODES) end = N_NODES;
    int s = 0;
    for (int i = begin; i < end && i >= begin; i++) s += cnt[i];
    part[t] = s;
    __syncthreads();
    for (int off = 1; off < T; off <<= 1) {
        int v = (t >= off) ? part[t - off] : 0;
        __syncthreads();
        part[t] += v;
        __syncthreads();
    }
    int run = (t == 0) ? 0 : part[t - 1];
    for (int i = begin; i < end && i >= begin; i++) {
        rowptr[i] = run;
        run += cnt[i];
    }
    if (end == N_NODES) rowptr[N_NODES] = run;
}

__global__ void k_fill(const int* __restrict__ src, const int* __restrict__ dst,
                       const float* __restrict__ ew, const float* __restrict__ dinv,
                       const int* __restrict__ rowptr, int* __restrict__ fill,
                       int* __restrict__ col, float* __restrict__ nrm) {
    int e = blockIdx.x * blockDim.x + threadIdx.x;
    if (e >= N_EDGES) return;
    int d = dst[e];
    int s = src[e];
    int pos = rowptr[d] + atomicAdd(&fill[d], 1);
    col[pos] = s;
    nrm[pos] = dinv[s] * ew[e] * dinv[d];
}

// ---------------------------------------------------------------------------
// Weight prep: W[K,N] f32 -> Wt[N, 2K] bf16 (hi plane cols 0..K-1, lo K..2K-1)
// Ranges: W1 = 128*256 = 32768, W2 = 256*256 = 65536, W3 = 256*128 = 32768.
// Total = 131072. (R3 bug: W3 range was 65536 -> OOB reads + Wb3 corruption.)
// ---------------------------------------------------------------------------

#define WPREP_TOTAL 131072

__global__ void k_wprep(const float* __restrict__ W1, const float* __restrict__ W2,
                        const float* __restrict__ W3,
                        u16* __restrict__ B1, u16* __restrict__ B2, u16* __restrict__ B3) {
    int idx = blockIdx.x * blockDim.x + threadIdx.x;
    const float* W; u16* B; int K, N, base;
    if (idx < 32768)       { W = W1; B = B1; K = 128; N = 256; base = 0; }
    else if (idx < 98304)  { W = W2; B = B2; K = 256; N = 256; base = 32768; }
    else if (idx < 131072) { W = W3; B = B3; K = 256; N = 128; base = 98304; }
    else return;
    int p = idx - base;
    int n = p % N, k = p / N;
    float x = W[(size_t)k * N + n];
    u16 hi = f2bf(x);
    u16 lo = f2bf(x - bf2f(hi));
    B[(size_t)n * (2 * K) + k] = hi;
    B[(size_t)n * (2 * K) + K + k] = lo;
}

// ---------------------------------------------------------------------------
// Aggregation. OUTM: 0 = f32 out (+bias), 1 = bf16 hi/lo out [N, 2D]
// ---------------------------------------------------------------------------

template <int D, int OUTM, bool BIAS>
__global__ __launch_bounds__(256) void k_agg(const float* __restrict__ in,
                                             const int* __restrict__ rowptr,
                                             const int* __restrict__ col,
                                             const float* __restrict__ nrm,
                                             const float* __restrict__ dinv,
                                             const float* __restrict__ bias,
                                             void* __restrict__ outv) {
    int node = blockIdx.x * 4 + (threadIdx.x >> 6);
    int lane = threadIdx.x & 63;
    if (node >= N_NODES) return;
    float dn = dinv[node];
    float dd = dn * dn;
    int beg = rowptr[node], end = rowptr[node + 1];

    if (D == 256) {
        float4 sv = *(reinterpret_cast<const float4*>(in + (size_t)node * D) + lane);
        float ax = dd * sv.x, ay = dd * sv.y, az = dd * sv.z, aw = dd * sv.w;
        int p = beg;
        for (; p + 1 < end; p += 2) {
            int s0 = col[p], s1 = col[p + 1];
            float w0 = nrm[p], w1 = nrm[p + 1];
            float4 r0 = *(reinterpret_cast<const float4*>(in + (size_t)s0 * D) + lane);
            float4 r1 = *(reinterpret_cast<const float4*>(in + (size_t)s1 * D) + lane);
            ax += w0 * r0.x; ay += w0 * r0.y; az += w0 * r0.z; aw += w0 * r0.w;
            ax += w1 * r1.x; ay += w1 * r1.y; az += w1 * r1.z; aw += w1 * r1.w;
        }
        if (p < end) {
            int s0 = col[p];
            float w0 = nrm[p];
            float4 r0 = *(reinterpret_cast<const float4*>(in + (size_t)s0 * D) + lane);
            ax += w0 * r0.x; ay += w0 * r0.y; az += w0 * r0.z; aw += w0 * r0.w;
        }
        if (OUTM == 0) {
            float* out = (float*)outv;
            if (BIAS) {
                float4 b = *(reinterpret_cast<const float4*>(bias) + lane);
                ax += b.x; ay += b.y; az += b.z; aw += b.w;
            }
            float4 res; res.x = ax; res.y = ay; res.z = az; res.w = aw;
            *(reinterpret_cast<float4*>(out + (size_t)node * D) + lane) = res;
        } else {
            u16* out = (u16*)outv;  // [N, 512]
            u16 h0 = f2bf(ax), h1 = f2bf(ay), h2 = f2bf(az), h3 = f2bf(aw);
            ushort4 hv; hv.x = h0; hv.y = h1; hv.z = h2; hv.w = h3;
            ushort4 lv;
            lv.x = f2bf(ax - bf2f(h0)); lv.y = f2bf(ay - bf2f(h1));
            lv.z = f2bf(az - bf2f(h2)); lv.w = f2bf(aw - bf2f(h3));
            *(reinterpret_cast<ushort4*>(out + (size_t)node * 512) + lane) = hv;
            *(reinterpret_cast<ushort4*>(out + (size_t)node * 512 + 256) + lane) = lv;
        }
    } else {  // D == 128
        float2 sv = *(reinterpret_cast<const float2*>(in + (size_t)node * D) + lane);
        float ax = dd * sv.x, ay = dd * sv.y;
        int p = beg;
        for (; p + 1 < end; p += 2) {
            int s0 = col[p], s1 = col[p + 1];
            float w0 = nrm[p], w1 = nrm[p + 1];
            float2 r0 = *(reinterpret_cast<const float2*>(in + (size_t)s0 * D) + lane);
            float2 r1 = *(reinterpret_cast<const float2*>(in + (size_t)s1 * D) + lane);
            ax += w0 * r0.x; ay += w0 * r0.y;
            ax += w1 * r1.x; ay += w1 * r1.y;
        }
        if (p < end) {
            int s0 = col[p];
            float w0 = nrm[p];
            float2 r0 = *(reinterpret_cast<const float2*>(in + (size_t)s0 * D) + lane);
            ax += w0 * r0.x; ay += w0 * r0.y;
        }
        if (OUTM == 0) {
            float* out = (float*)outv;
            if (BIAS) {
                float2 b = *(reinterpret_cast<const float2*>(bias) + lane);
                ax += b.x; ay += b.y;
            }
            float2 res; res.x = ax; res.y = ay;
            *(reinterpret_cast<float2*>(out + (size_t)node * D) + lane) = res;
        } else {
            u16* out = (u16*)outv;  // [N, 256]
            u16 h0 = f2bf(ax), h1 = f2bf(ay);
            ushort2 hv; hv.x = h0; hv.y = h1;
            ushort2 lv; lv.x = f2bf(ax - bf2f(h0)); lv.y = f2bf(ay - bf2f(h1));
            *(reinterpret_cast<ushort2*>(out + (size_t)node * 256) + lane) = hv;
            *(reinterpret_cast<ushort2*>(out + (size_t)node * 256 + 128) + lane) = lv;
        }
    }
}

// ---------------------------------------------------------------------------
// Split-bf16 MFMA GEMM.
// A stored [M, 2K] bf16 (hi|lo), B stored [NN, 2K] bf16 (hi|lo, row n = W^T).
// Logical K' = 3K: seg0 Ah*Bh, seg1 Al*Bh, seg2 Ah*Bl (Al*Bl dropped, ~2^-18).
// Block 128x128, 4 waves, each 64x64 via 4x4 tiles of mfma_f32_16x16x32_bf16.
// LDS octet-swizzled: slot(row r, oct) = (r>>4)*512 + ((r&15)+oct*16)*8 ushorts
// -> fragment ds_read_b128 at g*512 + lane*8 (linear), staging writes balanced.
// OUT: 0 = f32 C[M,NN]; 1 = bf16 hi/lo C[M,2NN] (feeds next GEMM as A).
// ---------------------------------------------------------------------------

template <int OUT, bool BIAS, bool RELU>
__global__ __launch_bounds__(256) void k_gemm_bf(const u16* __restrict__ Ap,
                                                 const u16* __restrict__ Bp,
                                                 const float* __restrict__ bias,
                                                 void* __restrict__ Cv,
                                                 int M, int K, int NN) {
    const int KP2 = 2 * K;
    __shared__ u16 As[8 * 512];
    __shared__ u16 Bs[8 * 512];
    int tid = threadIdx.x;
    int bm = blockIdx.y * 128;
    int bn = blockIdx.x * 128;
    int l = tid & 63;
    int w = tid >> 6;
    int wr = w >> 1, wc = w & 1;

    f32x4 zero = {0.f, 0.f, 0.f, 0.f};
    f32x4 acc[4][4];
    #pragma unroll
    for (int i = 0; i < 4; i++)
        #pragma unroll
        for (int j = 0; j < 4; j++) acc[i][j] = zero;

    int sm = tid >> 2;     // row 0..63 (+64 on 2nd round)
    int soct = tid & 3;    // k-octet

    for (int k0 = 0; k0 < 3 * K; k0 += 32) {
        int ak = (k0 < 2 * K) ? k0 : k0 - 2 * K;
        int bk = (k0 < K) ? k0 : k0 - K;
        #pragma unroll
        for (int q = 0; q < 2; q++) {
            int r = sm + q * 64;
            int lds = (r >> 4) * 512 + ((r & 15) + soct * 16) * 8;
            int gr = bm + r;
            uint4 va = make_uint4(0u, 0u, 0u, 0u);
            if (gr < M)
                va = *reinterpret_cast<const uint4*>(Ap + (size_t)gr * KP2 + ak + soct * 8);
            *reinterpret_cast<uint4*>(&As[lds]) = va;
            uint4 vb = *reinterpret_cast<const uint4*>(Bp + (size_t)(bn + r) * KP2 + bk + soct * 8);
            *reinterpret_cast<uint4*>(&Bs[lds]) = vb;
        }
        __syncthreads();
        bf16x8 a[4], b[4];
        #pragma unroll
        for (int i = 0; i < 4; i++)
            a[i] = *reinterpret_cast<const bf16x8*>(&As[(wr * 4 + i) * 512 + l * 8]);
        #pragma unroll
        for (int j = 0; j < 4; j++)
            b[j] = *reinterpret_cast<const bf16x8*>(&Bs[(wc * 4 + j) * 512 + l * 8]);
        #pragma unroll
        for (int i = 0; i < 4; i++)
            #pragma unroll
            for (int j = 0; j < 4; j++)
                acc[i][j] = __builtin_amdgcn_mfma_f32_16x16x32_bf16(a[i], b[j], acc[i][j], 0, 0, 0);
        __syncthreads();
    }

    // epilogue: C/D layout col = lane&15, row = (lane>>4)*4 + reg
    int cl = l & 15;
    int rq = (l >> 4) * 4;
    float bv[4];
    #pragma unroll
    for (int j = 0; j < 4; j++) {
        int gc = bn + wc * 64 + j * 16 + cl;
        bv[j] = BIAS ? bias[gc] : 0.f;
    }
    #pragma unroll
    for (int i = 0; i < 4; i++) {
        #pragma unroll
        for (int r = 0; r < 4; r++) {
            int grow = bm + wr * 64 + i * 16 + rq + r;
            if (grow >= M) continue;
            #pragma unroll
            for (int j = 0; j < 4; j++) {
                int gc = bn + wc * 64 + j * 16 + cl;
                float v = acc[i][j][r];
                if (BIAS) v += bv[j];
                if (RELU) v = fmaxf(v, 0.f);
                if (OUT == 0) {
                    ((float*)Cv)[(size_t)grow * NN + gc] = v;
                } else {
                    u16* C = (u16*)Cv;  // [M, 2*NN]
                    u16 hi = f2bf(v);
                    u16 lo = f2bf(v - bf2f(hi));
                    C[(size_t)grow * (2 * NN) + gc] = hi;
                    C[(size_t)grow * (2 * NN) + NN + gc] = lo;
                }
            }
        }
    }
}

// ---------------------------------------------------------------------------
// launch
// ---------------------------------------------------------------------------

extern "C" void kernel_launch(void* const* d_in, const int* in_sizes, int n_in,
                              void* d_out, int out_size, void* d_ws, size_t ws_size,
                              hipStream_t stream) {
    const float* x   = (const float*)d_in[0];
    const int*   ei  = (const int*)d_in[1];
    const float* wts = (const float*)d_in[2];
    const float* W1  = (const float*)d_in[3];
    const float* b1  = (const float*)d_in[4];
    const float* W2  = (const float*)d_in[5];
    const float* b2  = (const float*)d_in[6];
    const float* W3  = (const float*)d_in[7];
    const float* b3  = (const float*)d_in[8];
    float* out = (float*)d_out;
    const int* src = ei;
    const int* dst = ei + N_EDGES;

    float* bufA   = (float*)d_ws;                         // N*256 f32 worth
    float* bufB   = bufA + (size_t)N_NODES * D_HID;       // N*256 f32 worth
    float* ew     = bufB + (size_t)N_NODES * D_HID;       // [E]
    float* deg    = ew + N_EDGES;                         // [N] -> dinv
    int*   cnt    = (int*)(deg + N_NODES);                // [N]
    int*   fill   = cnt + N_NODES;                        // [N]
    int*   rowptr = fill + N_NODES;                       // [N+1]
    int*   col    = rowptr + (N_NODES + 2);               // [E]
    float* nrm    = (float*)(col + N_EDGES);              // [E]
    u16*   Wb1    = (u16*)(nrm + N_EDGES);                // [256*256]
    u16*   Wb2    = Wb1 + 256 * 256;                      // [256*512]
    u16*   Wb3    = Wb2 + 256 * 512;                      // [128*512]

    hipMemsetAsync(deg, 0, sizeof(float) * N_NODES + sizeof(int) * 2 * N_NODES, stream);

    int ethreads = 256;
    int eblocks = (N_EDGES + ethreads - 1) / ethreads;
    k_edge_prep<<<eblocks, ethreads, 0, stream>>>(src, dst, wts, ew, deg, cnt);
    k_dinv<<<(N_NODES + 255) / 256, 256, 0, stream>>>(deg);
    k_scan<<<1, 1024, 0, stream>>>(cnt, rowptr);
    k_fill<<<eblocks, ethreads, 0, stream>>>(src, dst, ew, deg, rowptr, fill, col, nrm);
    k_wprep<<<(WPREP_TOTAL + 255) / 256, 256, 0, stream>>>(W1, W2, W3, Wb1, Wb2, Wb3);

    int aggBlocks = (N_NODES + 3) / 4;
    int gy = (N_NODES + 127) / 128;  // 391

    // L1: A1' = hilo(A.x) [N,256]bf16 ; h1 = relu(A1' @ W1' + b1) f32 [N,256]
    k_agg<128, 1, false><<<aggBlocks, 256, 0, stream>>>(x, rowptr, col, nrm, deg, nullptr, bufA);
    {
        dim3 g(2, gy);
        k_gemm_bf<0, true, true><<<g, 256, 0, stream>>>((const u16*)bufA, Wb1, b1, bufB,
                                                        N_NODES, D_IN, D_HID);
    }
    // L2: A2' = hilo(A.h1) [N,512]bf16 ; h2hl = hilo(relu(A2' @ W2' + b2)) [N,512]bf16
    k_agg<256, 1, false><<<aggBlocks, 256, 0, stream>>>(bufB, rowptr, col, nrm, deg, nullptr, bufA);
    {
        dim3 g(2, gy);
        k_gemm_bf<1, true, true><<<g, 256, 0, stream>>>((const u16*)bufA, Wb2, b2, bufB,
                                                        N_NODES, D_HID, D_HID);
    }
    // L3: y3 = h2hl @ W3' f32 [N,128] ; out = A.y3 + b3
    {
        dim3 g(1, gy);
        k_gemm_bf<0, false, false><<<g, 256, 0, stream>>>((const u16*)bufB, Wb3, nullptr, bufA,
                                                          N_NODES, D_HID, D_OUT);
    }
    k_agg<128, 0, true><<<aggBlocks, 256, 0, stream>>>(bufA, rowptr, col, nrm, deg, b3, out);
}

// Round 5
// 573.447 us; speedup vs baseline: 1.3570x; 1.0076x over previous
//
#include <hip/hip_runtime.h>
#include <math.h>

#define N_NODES 50000
#define N_EDGES 600000
#define D_IN    128
#define D_HID   256
#define D_OUT   128

typedef unsigned short u16;
typedef __attribute__((ext_vector_type(8))) short bf16x8;
typedef __attribute__((ext_vector_type(4))) float f32x4;

__device__ __forceinline__ u16 f2bf(float x) {
    unsigned int u = __float_as_uint(x);
    unsigned int r = (u + 0x7fffu + ((u >> 16) & 1u)) >> 16;
    return (u16)r;
}
__device__ __forceinline__ float bf2f(u16 h) {
    return __uint_as_float(((unsigned int)h) << 16);
}

// ---------------------------------------------------------------------------
// Setup: softplus, degree, dinv, CSR (packed {src, norm} records)
// ---------------------------------------------------------------------------

__global__ void k_edge_prep(const int* __restrict__ src, const int* __restrict__ dst,
                            const float* __restrict__ w, float* __restrict__ ew,
                            float* __restrict__ deg, int* __restrict__ cnt) {
    int e = blockIdx.x * blockDim.x + threadIdx.x;
    if (e >= N_EDGES) return;
    float x = w[e];
    float sp = fmaxf(x, 0.f) + log1pf(expf(-fabsf(x)));
    ew[e] = sp;
    int d = dst[e];
    atomicAdd(&deg[d], sp);
    atomicAdd(&cnt[d], 1);
    (void)src;
}

__global__ void k_dinv(float* __restrict__ deg) {
    int n = blockIdx.x * blockDim.x + threadIdx.x;
    if (n >= N_NODES) return;
    deg[n] = rsqrtf(deg[n] + 1.0f);
}

__global__ void k_scan(const int* __restrict__ cnt, int* __restrict__ rowptr) {
    __shared__ int part[1024];
    const int T = 1024;
    int t = threadIdx.x;
    const int chunk = (N_NODES + T - 1) / T;
    int begin = t * chunk;
    int end = begin + chunk; if (end > N_NODES) end = N_NODES;
    int s = 0;
    for (int i = begin; i < end && i >= begin; i++) s += cnt[i];
    part[t] = s;
    __syncthreads();
    for (int off = 1; off < T; off <<= 1) {
        int v = (t >= off) ? part[t - off] : 0;
        __syncthreads();
        part[t] += v;
        __syncthreads();
    }
    int run = (t == 0) ? 0 : part[t - 1];
    for (int i = begin; i < end && i >= begin; i++) {
        rowptr[i] = run;
        run += cnt[i];
    }
    if (end == N_NODES) rowptr[N_NODES] = run;
}

__global__ void k_fill(const int* __restrict__ src, const int* __restrict__ dst,
                       const float* __restrict__ ew, const float* __restrict__ dinv,
                       const int* __restrict__ rowptr, int* __restrict__ fill,
                       int2* __restrict__ ecsr) {
    int e = blockIdx.x * blockDim.x + threadIdx.x;
    if (e >= N_EDGES) return;
    int d = dst[e];
    int s = src[e];
    int pos = rowptr[d] + atomicAdd(&fill[d], 1);
    float w = dinv[s] * ew[e] * dinv[d];
    ecsr[pos] = make_int2(s, __float_as_int(w));
}

// ---------------------------------------------------------------------------
// Weight prep: W[K,N] f32 -> Wt[N, 2K] bf16 (hi plane cols 0..K-1, lo K..2K-1)
// Ranges: 32768 + 65536 + 32768 = 131072.
// ---------------------------------------------------------------------------

#define WPREP_TOTAL 131072

__global__ void k_wprep(const float* __restrict__ W1, const float* __restrict__ W2,
                        const float* __restrict__ W3,
                        u16* __restrict__ B1, u16* __restrict__ B2, u16* __restrict__ B3) {
    int idx = blockIdx.x * blockDim.x + threadIdx.x;
    const float* W; u16* B; int K, N, base;
    if (idx < 32768)       { W = W1; B = B1; K = 128; N = 256; base = 0; }
    else if (idx < 98304)  { W = W2; B = B2; K = 256; N = 256; base = 32768; }
    else if (idx < 131072) { W = W3; B = B3; K = 256; N = 128; base = 98304; }
    else return;
    int p = idx - base;
    int n = p % N, k = p / N;
    float x = W[(size_t)k * N + n];
    u16 hi = f2bf(x);
    u16 lo = f2bf(x - bf2f(hi));
    B[(size_t)n * (2 * K) + k] = hi;
    B[(size_t)n * (2 * K) + K + k] = lo;
}

// ---------------------------------------------------------------------------
// Aggregation. OUTM: 0 = f32 out (+bias), 1 = bf16 hi/lo out [N, 2D].
// One wave per node. Software-pipelined gather: indices for a group loaded
// before the row gathers issue -> 4 (D=256) / 8 (D=128) rows in flight/wave.
// ---------------------------------------------------------------------------

template <int D, int OUTM, bool BIAS>
__global__ __launch_bounds__(256) void k_agg(const float* __restrict__ in,
                                             const int* __restrict__ rowptr,
                                             const int2* __restrict__ ecsr,
                                             const float* __restrict__ dinv,
                                             const float* __restrict__ bias,
                                             void* __restrict__ outv) {
    int node = blockIdx.x * 4 + (threadIdx.x >> 6);
    int lane = threadIdx.x & 63;
    if (node >= N_NODES) return;
    float dn = dinv[node];
    float dd = dn * dn;
    int beg = rowptr[node], end = rowptr[node + 1];

    if (D == 256) {
        float4 sv = *(reinterpret_cast<const float4*>(in + (size_t)node * D) + lane);
        float ax = dd * sv.x, ay = dd * sv.y, az = dd * sv.z, aw = dd * sv.w;
        int p = beg;
        for (; p + 4 <= end; p += 4) {
            int2 e0 = ecsr[p], e1 = ecsr[p + 1], e2 = ecsr[p + 2], e3 = ecsr[p + 3];
            float w0 = __int_as_float(e0.y), w1 = __int_as_float(e1.y);
            float w2 = __int_as_float(e2.y), w3 = __int_as_float(e3.y);
            float4 r0 = *(reinterpret_cast<const float4*>(in + (size_t)e0.x * D) + lane);
            float4 r1 = *(reinterpret_cast<const float4*>(in + (size_t)e1.x * D) + lane);
            float4 r2 = *(reinterpret_cast<const float4*>(in + (size_t)e2.x * D) + lane);
            float4 r3 = *(reinterpret_cast<const float4*>(in + (size_t)e3.x * D) + lane);
            ax += w0 * r0.x; ay += w0 * r0.y; az += w0 * r0.z; aw += w0 * r0.w;
            ax += w1 * r1.x; ay += w1 * r1.y; az += w1 * r1.z; aw += w1 * r1.w;
            ax += w2 * r2.x; ay += w2 * r2.y; az += w2 * r2.z; aw += w2 * r2.w;
            ax += w3 * r3.x; ay += w3 * r3.y; az += w3 * r3.z; aw += w3 * r3.w;
        }
        for (; p < end; p++) {
            int2 e0 = ecsr[p];
            float w0 = __int_as_float(e0.y);
            float4 r0 = *(reinterpret_cast<const float4*>(in + (size_t)e0.x * D) + lane);
            ax += w0 * r0.x; ay += w0 * r0.y; az += w0 * r0.z; aw += w0 * r0.w;
        }
        if (OUTM == 0) {
            float* out = (float*)outv;
            if (BIAS) {
                float4 b = *(reinterpret_cast<const float4*>(bias) + lane);
                ax += b.x; ay += b.y; az += b.z; aw += b.w;
            }
            float4 res; res.x = ax; res.y = ay; res.z = az; res.w = aw;
            *(reinterpret_cast<float4*>(out + (size_t)node * D) + lane) = res;
        } else {
            u16* out = (u16*)outv;  // [N, 512]
            u16 h0 = f2bf(ax), h1 = f2bf(ay), h2 = f2bf(az), h3 = f2bf(aw);
            ushort4 hv; hv.x = h0; hv.y = h1; hv.z = h2; hv.w = h3;
            ushort4 lv;
            lv.x = f2bf(ax - bf2f(h0)); lv.y = f2bf(ay - bf2f(h1));
            lv.z = f2bf(az - bf2f(h2)); lv.w = f2bf(aw - bf2f(h3));
            *(reinterpret_cast<ushort4*>(out + (size_t)node * 512) + lane) = hv;
            *(reinterpret_cast<ushort4*>(out + (size_t)node * 512 + 256) + lane) = lv;
        }
    } else {  // D == 128
        float2 sv = *(reinterpret_cast<const float2*>(in + (size_t)node * D) + lane);
        float ax = dd * sv.x, ay = dd * sv.y;
        int p = beg;
        for (; p + 8 <= end; p += 8) {
            int2 e0 = ecsr[p],     e1 = ecsr[p + 1], e2 = ecsr[p + 2], e3 = ecsr[p + 3];
            int2 e4 = ecsr[p + 4], e5 = ecsr[p + 5], e6 = ecsr[p + 6], e7 = ecsr[p + 7];
            float2 r0 = *(reinterpret_cast<const float2*>(in + (size_t)e0.x * D) + lane);
            float2 r1 = *(reinterpret_cast<const float2*>(in + (size_t)e1.x * D) + lane);
            float2 r2 = *(reinterpret_cast<const float2*>(in + (size_t)e2.x * D) + lane);
            float2 r3 = *(reinterpret_cast<const float2*>(in + (size_t)e3.x * D) + lane);
            float2 r4 = *(reinterpret_cast<const float2*>(in + (size_t)e4.x * D) + lane);
            float2 r5 = *(reinterpret_cast<const float2*>(in + (size_t)e5.x * D) + lane);
            float2 r6 = *(reinterpret_cast<const float2*>(in + (size_t)e6.x * D) + lane);
            float2 r7 = *(reinterpret_cast<const float2*>(in + (size_t)e7.x * D) + lane);
            ax += __int_as_float(e0.y) * r0.x; ay += __int_as_float(e0.y) * r0.y;
            ax += __int_as_float(e1.y) * r1.x; ay += __int_as_float(e1.y) * r1.y;
            ax += __int_as_float(e2.y) * r2.x; ay += __int_as_float(e2.y) * r2.y;
            ax += __int_as_float(e3.y) * r3.x; ay += __int_as_float(e3.y) * r3.y;
            ax += __int_as_float(e4.y) * r4.x; ay += __int_as_float(e4.y) * r4.y;
            ax += __int_as_float(e5.y) * r5.x; ay += __int_as_float(e5.y) * r5.y;
            ax += __int_as_float(e6.y) * r6.x; ay += __int_as_float(e6.y) * r6.y;
            ax += __int_as_float(e7.y) * r7.x; ay += __int_as_float(e7.y) * r7.y;
        }
        for (; p < end; p++) {
            int2 e0 = ecsr[p];
            float w0 = __int_as_float(e0.y);
            float2 r0 = *(reinterpret_cast<const float2*>(in + (size_t)e0.x * D) + lane);
            ax += w0 * r0.x; ay += w0 * r0.y;
        }
        if (OUTM == 0) {
            float* out = (float*)outv;
            if (BIAS) {
                float2 b = *(reinterpret_cast<const float2*>(bias) + lane);
                ax += b.x; ay += b.y;
            }
            float2 res; res.x = ax; res.y = ay;
            *(reinterpret_cast<float2*>(out + (size_t)node * D) + lane) = res;
        } else {
            u16* out = (u16*)outv;  // [N, 256]
            u16 h0 = f2bf(ax), h1 = f2bf(ay);
            ushort2 hv; hv.x = h0; hv.y = h1;
            ushort2 lv; lv.x = f2bf(ax - bf2f(h0)); lv.y = f2bf(ay - bf2f(h1));
            *(reinterpret_cast<ushort2*>(out + (size_t)node * 256) + lane) = hv;
            *(reinterpret_cast<ushort2*>(out + (size_t)node * 256 + 128) + lane) = lv;
        }
    }
}

// ---------------------------------------------------------------------------
// Split-bf16 MFMA GEMM (unchanged from R4).
// A [M,2K] bf16 hi|lo, B [NN,2K] bf16 hi|lo (row n = W^T). K' = 3K segments:
// Ah*Bh, Al*Bh, Ah*Bl. Block 128x128, 4 waves, 4x4 mfma_f32_16x16x32_bf16.
// ---------------------------------------------------------------------------

template <int OUT, bool BIAS, bool RELU>
__global__ __launch_bounds__(256) void k_gemm_bf(const u16* __restrict__ Ap,
                                                 const u16* __restrict__ Bp,
                                                 const float* __restrict__ bias,
                                                 void* __restrict__ Cv,
                                                 int M, int K, int NN) {
    const int KP2 = 2 * K;
    __shared__ u16 As[8 * 512];
    __shared__ u16 Bs[8 * 512];
    int tid = threadIdx.x;
    int bm = blockIdx.y * 128;
    int bn = blockIdx.x * 128;
    int l = tid & 63;
    int w = tid >> 6;
    int wr = w >> 1, wc = w & 1;

    f32x4 zero = {0.f, 0.f, 0.f, 0.f};
    f32x4 acc[4][4];
    #pragma unroll
    for (int i = 0; i < 4; i++)
        #pragma unroll
        for (int j = 0; j < 4; j++) acc[i][j] = zero;

    int sm = tid >> 2;
    int soct = tid & 3;

    for (int k0 = 0; k0 < 3 * K; k0 += 32) {
        int ak = (k0 < 2 * K) ? k0 : k0 - 2 * K;
        int bk = (k0 < K) ? k0 : k0 - K;
        #pragma unroll
        for (int q = 0; q < 2; q++) {
            int r = sm + q * 64;
            int lds = (r >> 4) * 512 + ((r & 15) + soct * 16) * 8;
            int gr = bm + r;
            uint4 va = make_uint4(0u, 0u, 0u, 0u);
            if (gr < M)
                va = *reinterpret_cast<const uint4*>(Ap + (size_t)gr * KP2 + ak + soct * 8);
            *reinterpret_cast<uint4*>(&As[lds]) = va;
            uint4 vb = *reinterpret_cast<const uint4*>(Bp + (size_t)(bn + r) * KP2 + bk + soct * 8);
            *reinterpret_cast<uint4*>(&Bs[lds]) = vb;
        }
        __syncthreads();
        bf16x8 a[4], b[4];
        #pragma unroll
        for (int i = 0; i < 4; i++)
            a[i] = *reinterpret_cast<const bf16x8*>(&As[(wr * 4 + i) * 512 + l * 8]);
        #pragma unroll
        for (int j = 0; j < 4; j++)
            b[j] = *reinterpret_cast<const bf16x8*>(&Bs[(wc * 4 + j) * 512 + l * 8]);
        #pragma unroll
        for (int i = 0; i < 4; i++)
            #pragma unroll
            for (int j = 0; j < 4; j++)
                acc[i][j] = __builtin_amdgcn_mfma_f32_16x16x32_bf16(a[i], b[j], acc[i][j], 0, 0, 0);
        __syncthreads();
    }

    int cl = l & 15;
    int rq = (l >> 4) * 4;
    float bv[4];
    #pragma unroll
    for (int j = 0; j < 4; j++) {
        int gc = bn + wc * 64 + j * 16 + cl;
        bv[j] = BIAS ? bias[gc] : 0.f;
    }
    #pragma unroll
    for (int i = 0; i < 4; i++) {
        #pragma unroll
        for (int r = 0; r < 4; r++) {
            int grow = bm + wr * 64 + i * 16 + rq + r;
            if (grow >= M) continue;
            #pragma unroll
            for (int j = 0; j < 4; j++) {
                int gc = bn + wc * 64 + j * 16 + cl;
                float v = acc[i][j][r];
                if (BIAS) v += bv[j];
                if (RELU) v = fmaxf(v, 0.f);
                if (OUT == 0) {
                    ((float*)Cv)[(size_t)grow * NN + gc] = v;
                } else {
                    u16* C = (u16*)Cv;  // [M, 2*NN]
                    u16 hi = f2bf(v);
                    u16 lo = f2bf(v - bf2f(hi));
                    C[(size_t)grow * (2 * NN) + gc] = hi;
                    C[(size_t)grow * (2 * NN) + NN + gc] = lo;
                }
            }
        }
    }
}

// ---------------------------------------------------------------------------
// launch
// ---------------------------------------------------------------------------

extern "C" void kernel_launch(void* const* d_in, const int* in_sizes, int n_in,
                              void* d_out, int out_size, void* d_ws, size_t ws_size,
                              hipStream_t stream) {
    const float* x   = (const float*)d_in[0];
    const int*   ei  = (const int*)d_in[1];
    const float* wts = (const float*)d_in[2];
    const float* W1  = (const float*)d_in[3];
    const float* b1  = (const float*)d_in[4];
    const float* W2  = (const float*)d_in[5];
    const float* b2  = (const float*)d_in[6];
    const float* W3  = (const float*)d_in[7];
    const float* b3  = (const float*)d_in[8];
    float* out = (float*)d_out;
    const int* src = ei;
    const int* dst = ei + N_EDGES;

    float* bufA   = (float*)d_ws;                         // N*256 f32 worth
    float* bufB   = bufA + (size_t)N_NODES * D_HID;       // N*256 f32 worth
    float* ew     = bufB + (size_t)N_NODES * D_HID;       // [E]
    float* deg    = ew + N_EDGES;                         // [N] -> dinv
    int*   cnt    = (int*)(deg + N_NODES);                // [N]
    int*   fill   = cnt + N_NODES;                        // [N]
    int*   rowptr = fill + N_NODES;                       // [N+1]
    int2*  ecsr   = (int2*)(rowptr + (N_NODES + 2));      // [E] packed {src, norm}
    u16*   Wb1    = (u16*)(ecsr + N_EDGES);               // [256*256]
    u16*   Wb2    = Wb1 + 256 * 256;                      // [256*512]
    u16*   Wb3    = Wb2 + 256 * 512;                      // [128*512]

    hipMemsetAsync(deg, 0, sizeof(float) * N_NODES + sizeof(int) * 2 * N_NODES, stream);

    int ethreads = 256;
    int eblocks = (N_EDGES + ethreads - 1) / ethreads;
    k_edge_prep<<<eblocks, ethreads, 0, stream>>>(src, dst, wts, ew, deg, cnt);
    k_dinv<<<(N_NODES + 255) / 256, 256, 0, stream>>>(deg);
    k_scan<<<1, 1024, 0, stream>>>(cnt, rowptr);
    k_fill<<<eblocks, ethreads, 0, stream>>>(src, dst, ew, deg, rowptr, fill, ecsr);
    k_wprep<<<(WPREP_TOTAL + 255) / 256, 256, 0, stream>>>(W1, W2, W3, Wb1, Wb2, Wb3);

    int aggBlocks = (N_NODES + 3) / 4;
    int gy = (N_NODES + 127) / 128;  // 391

    // L1: A1' = hilo(A.x) [N,256]bf16 ; h1 = relu(A1' @ W1' + b1) f32 [N,256]
    k_agg<128, 1, false><<<aggBlocks, 256, 0, stream>>>(x, rowptr, ecsr, deg, nullptr, bufA);
    {
        dim3 g(2, gy);
        k_gemm_bf<0, true, true><<<g, 256, 0, stream>>>((const u16*)bufA, Wb1, b1, bufB,
                                                        N_NODES, D_IN, D_HID);
    }
    // L2: A2' = hilo(A.h1) [N,512]bf16 ; h2hl = hilo(relu(A2' @ W2' + b2)) [N,512]bf16
    k_agg<256, 1, false><<<aggBlocks, 256, 0, stream>>>(bufB, rowptr, ecsr, deg, nullptr, bufA);
    {
        dim3 g(2, gy);
        k_gemm_bf<1, true, true><<<g, 256, 0, stream>>>((const u16*)bufA, Wb2, b2, bufB,
                                                        N_NODES, D_HID, D_HID);
    }
    // L3: y3 = h2hl @ W3' f32 [N,128] ; out = A.y3 + b3
    {
        dim3 g(1, gy);
        k_gemm_bf<0, false, false><<<g, 256, 0, stream>>>((const u16*)bufB, Wb3, nullptr, bufA,
                                                          N_NODES, D_HID, D_OUT);
    }
    k_agg<128, 0, true><<<aggBlocks, 256, 0, stream>>>(bufA, rowptr, ecsr, deg, b3, out);
}

// Round 6
// 509.325 us; speedup vs baseline: 1.5278x; 1.1259x over previous
//
#include <hip/hip_runtime.h>
#include <hip/hip_fp16.h>
#include <math.h>

#define N_NODES 50000
#define N_EDGES 600000
#define D_IN    128
#define D_HID   256
#define D_OUT   128

typedef unsigned short u16;
typedef __attribute__((ext_vector_type(8))) short bf16x8;
typedef __attribute__((ext_vector_type(4))) float f32x4;

__device__ __forceinline__ u16 f2bf(float x) {
    unsigned int u = __float_as_uint(x);
    unsigned int r = (u + 0x7fffu + ((u >> 16) & 1u)) >> 16;
    return (u16)r;
}
__device__ __forceinline__ float bf2f(u16 h) {
    return __uint_as_float(((unsigned int)h) << 16);
}
__device__ __forceinline__ float2 h2f2(unsigned int raw) {
    __half2 h = *reinterpret_cast<__half2*>(&raw);
    return __half22float2(h);
}

// ---------------------------------------------------------------------------
// Setup: softplus, degree, dinv, CSR (packed {src, norm} records)
// ---------------------------------------------------------------------------

__global__ void k_edge_prep(const int* __restrict__ src, const int* __restrict__ dst,
                            const float* __restrict__ w, float* __restrict__ ew,
                            float* __restrict__ deg, int* __restrict__ cnt) {
    int e = blockIdx.x * blockDim.x + threadIdx.x;
    if (e >= N_EDGES) return;
    float x = w[e];
    float sp = fmaxf(x, 0.f) + log1pf(expf(-fabsf(x)));
    ew[e] = sp;
    int d = dst[e];
    atomicAdd(&deg[d], sp);
    atomicAdd(&cnt[d], 1);
    (void)src;
}

__global__ void k_dinv(float* __restrict__ deg) {
    int n = blockIdx.x * blockDim.x + threadIdx.x;
    if (n >= N_NODES) return;
    deg[n] = rsqrtf(deg[n] + 1.0f);
}

__global__ void k_scan(const int* __restrict__ cnt, int* __restrict__ rowptr) {
    __shared__ int part[1024];
    const int T = 1024;
    int t = threadIdx.x;
    const int chunk = (N_NODES + T - 1) / T;
    int begin = t * chunk;
    int end = begin + chunk; if (end > N_NODES) end = N_NODES;
    int s = 0;
    for (int i = begin; i < end && i >= begin; i++) s += cnt[i];
    part[t] = s;
    __syncthreads();
    for (int off = 1; off < T; off <<= 1) {
        int v = (t >= off) ? part[t - off] : 0;
        __syncthreads();
        part[t] += v;
        __syncthreads();
    }
    int run = (t == 0) ? 0 : part[t - 1];
    for (int i = begin; i < end && i >= begin; i++) {
        rowptr[i] = run;
        run += cnt[i];
    }
    if (end == N_NODES) rowptr[N_NODES] = run;
}

__global__ void k_fill(const int* __restrict__ src, const int* __restrict__ dst,
                       const float* __restrict__ ew, const float* __restrict__ dinv,
                       const int* __restrict__ rowptr, int* __restrict__ fill,
                       int2* __restrict__ ecsr) {
    int e = blockIdx.x * blockDim.x + threadIdx.x;
    if (e >= N_EDGES) return;
    int d = dst[e];
    int s = src[e];
    int pos = rowptr[d] + atomicAdd(&fill[d], 1);
    float w = dinv[s] * ew[e] * dinv[d];
    ecsr[pos] = make_int2(s, __float_as_int(w));
}

// ---------------------------------------------------------------------------
// Weight prep: W[K,N] f32 -> Wt[N, 2K] bf16 (hi plane cols 0..K-1, lo K..2K-1)
// ---------------------------------------------------------------------------

#define WPREP_TOTAL 131072

__global__ void k_wprep(const float* __restrict__ W1, const float* __restrict__ W2,
                        const float* __restrict__ W3,
                        u16* __restrict__ B1, u16* __restrict__ B2, u16* __restrict__ B3) {
    int idx = blockIdx.x * blockDim.x + threadIdx.x;
    const float* W; u16* B; int K, N, base;
    if (idx < 32768)       { W = W1; B = B1; K = 128; N = 256; base = 0; }
    else if (idx < 98304)  { W = W2; B = B2; K = 256; N = 256; base = 32768; }
    else if (idx < 131072) { W = W3; B = B3; K = 256; N = 128; base = 98304; }
    else return;
    int p = idx - base;
    int n = p % N, k = p / N;
    float x = W[(size_t)k * N + n];
    u16 hi = f2bf(x);
    u16 lo = f2bf(x - bf2f(hi));
    B[(size_t)n * (2 * K) + k] = hi;
    B[(size_t)n * (2 * K) + K + k] = lo;
}

// ---------------------------------------------------------------------------
// Aggregation. INF: 0 = f32 rows, 1 = fp16 rows. OUTM: 0 = f32 (+bias),
// 1 = bf16 hi/lo [N, 2D]. One wave per node, 4-deep gather pipeline.
// ---------------------------------------------------------------------------

template <int D, int INF, int OUTM, bool BIAS>
__global__ __launch_bounds__(256) void k_agg(const void* __restrict__ inv,
                                             const int* __restrict__ rowptr,
                                             const int2* __restrict__ ecsr,
                                             const float* __restrict__ dinv,
                                             const float* __restrict__ bias,
                                             void* __restrict__ outv) {
    int node = blockIdx.x * 4 + (threadIdx.x >> 6);
    int lane = threadIdx.x & 63;
    if (node >= N_NODES) return;
    float dn = dinv[node];
    float dd = dn * dn;
    int beg = rowptr[node], end = rowptr[node + 1];

    if (D == 256) {
        const float* inf = (const float*)inv;
        const u16* inh = (const u16*)inv;
        // self row: features 4*lane .. 4*lane+3
        float sx, sy, sz, sw;
        if (INF == 0) {
            float4 sv = *(reinterpret_cast<const float4*>(inf + (size_t)node * D) + lane);
            sx = sv.x; sy = sv.y; sz = sv.z; sw = sv.w;
        } else {
            uint2 raw = *reinterpret_cast<const uint2*>(inh + (size_t)node * D + lane * 4);
            float2 f01 = h2f2(raw.x), f23 = h2f2(raw.y);
            sx = f01.x; sy = f01.y; sz = f23.x; sw = f23.y;
        }
        float ax = dd * sx, ay = dd * sy, az = dd * sz, aw = dd * sw;
        int p = beg;
        for (; p + 4 <= end; p += 4) {
            int2 e0 = ecsr[p], e1 = ecsr[p + 1], e2 = ecsr[p + 2], e3 = ecsr[p + 3];
            float w0 = __int_as_float(e0.y), w1 = __int_as_float(e1.y);
            float w2 = __int_as_float(e2.y), w3 = __int_as_float(e3.y);
            if (INF == 0) {
                float4 r0 = *(reinterpret_cast<const float4*>(inf + (size_t)e0.x * D) + lane);
                float4 r1 = *(reinterpret_cast<const float4*>(inf + (size_t)e1.x * D) + lane);
                float4 r2 = *(reinterpret_cast<const float4*>(inf + (size_t)e2.x * D) + lane);
                float4 r3 = *(reinterpret_cast<const float4*>(inf + (size_t)e3.x * D) + lane);
                ax += w0 * r0.x; ay += w0 * r0.y; az += w0 * r0.z; aw += w0 * r0.w;
                ax += w1 * r1.x; ay += w1 * r1.y; az += w1 * r1.z; aw += w1 * r1.w;
                ax += w2 * r2.x; ay += w2 * r2.y; az += w2 * r2.z; aw += w2 * r2.w;
                ax += w3 * r3.x; ay += w3 * r3.y; az += w3 * r3.z; aw += w3 * r3.w;
            } else {
                uint2 q0 = *reinterpret_cast<const uint2*>(inh + (size_t)e0.x * D + lane * 4);
                uint2 q1 = *reinterpret_cast<const uint2*>(inh + (size_t)e1.x * D + lane * 4);
                uint2 q2 = *reinterpret_cast<const uint2*>(inh + (size_t)e2.x * D + lane * 4);
                uint2 q3 = *reinterpret_cast<const uint2*>(inh + (size_t)e3.x * D + lane * 4);
                float2 a0 = h2f2(q0.x), b0 = h2f2(q0.y);
                float2 a1 = h2f2(q1.x), b1 = h2f2(q1.y);
                float2 a2 = h2f2(q2.x), b2 = h2f2(q2.y);
                float2 a3 = h2f2(q3.x), b3 = h2f2(q3.y);
                ax += w0 * a0.x; ay += w0 * a0.y; az += w0 * b0.x; aw += w0 * b0.y;
                ax += w1 * a1.x; ay += w1 * a1.y; az += w1 * b1.x; aw += w1 * b1.y;
                ax += w2 * a2.x; ay += w2 * a2.y; az += w2 * b2.x; aw += w2 * b2.y;
                ax += w3 * a3.x; ay += w3 * a3.y; az += w3 * b3.x; aw += w3 * b3.y;
            }
        }
        for (; p < end; p++) {
            int2 e0 = ecsr[p];
            float w0 = __int_as_float(e0.y);
            if (INF == 0) {
                float4 r0 = *(reinterpret_cast<const float4*>(inf + (size_t)e0.x * D) + lane);
                ax += w0 * r0.x; ay += w0 * r0.y; az += w0 * r0.z; aw += w0 * r0.w;
            } else {
                uint2 q0 = *reinterpret_cast<const uint2*>(inh + (size_t)e0.x * D + lane * 4);
                float2 a0 = h2f2(q0.x), b0 = h2f2(q0.y);
                ax += w0 * a0.x; ay += w0 * a0.y; az += w0 * b0.x; aw += w0 * b0.y;
            }
        }
        if (OUTM == 0) {
            float* out = (float*)outv;
            if (BIAS) {
                float4 b = *(reinterpret_cast<const float4*>(bias) + lane);
                ax += b.x; ay += b.y; az += b.z; aw += b.w;
            }
            float4 res; res.x = ax; res.y = ay; res.z = az; res.w = aw;
            *(reinterpret_cast<float4*>(out + (size_t)node * D) + lane) = res;
        } else {
            u16* out = (u16*)outv;  // [N, 512]
            u16 h0 = f2bf(ax), h1 = f2bf(ay), h2 = f2bf(az), h3 = f2bf(aw);
            ushort4 hv; hv.x = h0; hv.y = h1; hv.z = h2; hv.w = h3;
            ushort4 lv;
            lv.x = f2bf(ax - bf2f(h0)); lv.y = f2bf(ay - bf2f(h1));
            lv.z = f2bf(az - bf2f(h2)); lv.w = f2bf(aw - bf2f(h3));
            *(reinterpret_cast<ushort4*>(out + (size_t)node * 512) + lane) = hv;
            *(reinterpret_cast<ushort4*>(out + (size_t)node * 512 + 256) + lane) = lv;
        }
    } else {  // D == 128, features 2*lane, 2*lane+1 per lane
        const float* inf = (const float*)inv;
        const u16* inh = (const u16*)inv;
        float sx, sy;
        if (INF == 0) {
            float2 sv = *(reinterpret_cast<const float2*>(inf + (size_t)node * D) + lane);
            sx = sv.x; sy = sv.y;
        } else {
            unsigned int raw = *reinterpret_cast<const unsigned int*>(inh + (size_t)node * D + lane * 2);
            float2 f = h2f2(raw);
            sx = f.x; sy = f.y;
        }
        float ax = dd * sx, ay = dd * sy;
        int p = beg;
        for (; p + 4 <= end; p += 4) {
            int2 e0 = ecsr[p], e1 = ecsr[p + 1], e2 = ecsr[p + 2], e3 = ecsr[p + 3];
            float w0 = __int_as_float(e0.y), w1 = __int_as_float(e1.y);
            float w2 = __int_as_float(e2.y), w3 = __int_as_float(e3.y);
            if (INF == 0) {
                float2 r0 = *(reinterpret_cast<const float2*>(inf + (size_t)e0.x * D) + lane);
                float2 r1 = *(reinterpret_cast<const float2*>(inf + (size_t)e1.x * D) + lane);
                float2 r2 = *(reinterpret_cast<const float2*>(inf + (size_t)e2.x * D) + lane);
                float2 r3 = *(reinterpret_cast<const float2*>(inf + (size_t)e3.x * D) + lane);
                ax += w0 * r0.x; ay += w0 * r0.y;
                ax += w1 * r1.x; ay += w1 * r1.y;
                ax += w2 * r2.x; ay += w2 * r2.y;
                ax += w3 * r3.x; ay += w3 * r3.y;
            } else {
                unsigned int q0 = *reinterpret_cast<const unsigned int*>(inh + (size_t)e0.x * D + lane * 2);
                unsigned int q1 = *reinterpret_cast<const unsigned int*>(inh + (size_t)e1.x * D + lane * 2);
                unsigned int q2 = *reinterpret_cast<const unsigned int*>(inh + (size_t)e2.x * D + lane * 2);
                unsigned int q3 = *reinterpret_cast<const unsigned int*>(inh + (size_t)e3.x * D + lane * 2);
                float2 f0 = h2f2(q0), f1 = h2f2(q1), f2 = h2f2(q2), f3 = h2f2(q3);
                ax += w0 * f0.x; ay += w0 * f0.y;
                ax += w1 * f1.x; ay += w1 * f1.y;
                ax += w2 * f2.x; ay += w2 * f2.y;
                ax += w3 * f3.x; ay += w3 * f3.y;
            }
        }
        for (; p < end; p++) {
            int2 e0 = ecsr[p];
            float w0 = __int_as_float(e0.y);
            if (INF == 0) {
                float2 r0 = *(reinterpret_cast<const float2*>(inf + (size_t)e0.x * D) + lane);
                ax += w0 * r0.x; ay += w0 * r0.y;
            } else {
                unsigned int q0 = *reinterpret_cast<const unsigned int*>(inh + (size_t)e0.x * D + lane * 2);
                float2 f0 = h2f2(q0);
                ax += w0 * f0.x; ay += w0 * f0.y;
            }
        }
        if (OUTM == 0) {
            float* out = (float*)outv;
            if (BIAS) {
                float2 b = *(reinterpret_cast<const float2*>(bias) + lane);
                ax += b.x; ay += b.y;
            }
            float2 res; res.x = ax; res.y = ay;
            *(reinterpret_cast<float2*>(out + (size_t)node * D) + lane) = res;
        } else {
            u16* out = (u16*)outv;  // [N, 256]
            u16 h0 = f2bf(ax), h1 = f2bf(ay);
            ushort2 hv; hv.x = h0; hv.y = h1;
            ushort2 lv; lv.x = f2bf(ax - bf2f(h0)); lv.y = f2bf(ay - bf2f(h1));
            *(reinterpret_cast<ushort2*>(out + (size_t)node * 256) + lane) = hv;
            *(reinterpret_cast<ushort2*>(out + (size_t)node * 256 + 128) + lane) = lv;
        }
    }
}

// ---------------------------------------------------------------------------
// Split-bf16 MFMA GEMM. OUT: 0 = f32, 1 = bf16 hi/lo [M,2NN], 2 = fp16 [M,NN].
// ---------------------------------------------------------------------------

template <int OUT, bool BIAS, bool RELU>
__global__ __launch_bounds__(256) void k_gemm_bf(const u16* __restrict__ Ap,
                                                 const u16* __restrict__ Bp,
                                                 const float* __restrict__ bias,
                                                 void* __restrict__ Cv,
                                                 int M, int K, int NN) {
    const int KP2 = 2 * K;
    __shared__ u16 As[8 * 512];
    __shared__ u16 Bs[8 * 512];
    int tid = threadIdx.x;
    int bm = blockIdx.y * 128;
    int bn = blockIdx.x * 128;
    int l = tid & 63;
    int w = tid >> 6;
    int wr = w >> 1, wc = w & 1;

    f32x4 zero = {0.f, 0.f, 0.f, 0.f};
    f32x4 acc[4][4];
    #pragma unroll
    for (int i = 0; i < 4; i++)
        #pragma unroll
        for (int j = 0; j < 4; j++) acc[i][j] = zero;

    int sm = tid >> 2;
    int soct = tid & 3;

    for (int k0 = 0; k0 < 3 * K; k0 += 32) {
        int ak = (k0 < 2 * K) ? k0 : k0 - 2 * K;
        int bk = (k0 < K) ? k0 : k0 - K;
        #pragma unroll
        for (int q = 0; q < 2; q++) {
            int r = sm + q * 64;
            int lds = (r >> 4) * 512 + ((r & 15) + soct * 16) * 8;
            int gr = bm + r;
            uint4 va = make_uint4(0u, 0u, 0u, 0u);
            if (gr < M)
                va = *reinterpret_cast<const uint4*>(Ap + (size_t)gr * KP2 + ak + soct * 8);
            *reinterpret_cast<uint4*>(&As[lds]) = va;
            uint4 vb = *reinterpret_cast<const uint4*>(Bp + (size_t)(bn + r) * KP2 + bk + soct * 8);
            *reinterpret_cast<uint4*>(&Bs[lds]) = vb;
        }
        __syncthreads();
        bf16x8 a[4], b[4];
        #pragma unroll
        for (int i = 0; i < 4; i++)
            a[i] = *reinterpret_cast<const bf16x8*>(&As[(wr * 4 + i) * 512 + l * 8]);
        #pragma unroll
        for (int j = 0; j < 4; j++)
            b[j] = *reinterpret_cast<const bf16x8*>(&Bs[(wc * 4 + j) * 512 + l * 8]);
        #pragma unroll
        for (int i = 0; i < 4; i++)
            #pragma unroll
            for (int j = 0; j < 4; j++)
                acc[i][j] = __builtin_amdgcn_mfma_f32_16x16x32_bf16(a[i], b[j], acc[i][j], 0, 0, 0);
        __syncthreads();
    }

    int cl = l & 15;
    int rq = (l >> 4) * 4;
    float bv[4];
    #pragma unroll
    for (int j = 0; j < 4; j++) {
        int gc = bn + wc * 64 + j * 16 + cl;
        bv[j] = BIAS ? bias[gc] : 0.f;
    }
    #pragma unroll
    for (int i = 0; i < 4; i++) {
        #pragma unroll
        for (int r = 0; r < 4; r++) {
            int grow = bm + wr * 64 + i * 16 + rq + r;
            if (grow >= M) continue;
            #pragma unroll
            for (int j = 0; j < 4; j++) {
                int gc = bn + wc * 64 + j * 16 + cl;
                float v = acc[i][j][r];
                if (BIAS) v += bv[j];
                if (RELU) v = fmaxf(v, 0.f);
                if (OUT == 0) {
                    ((float*)Cv)[(size_t)grow * NN + gc] = v;
                } else if (OUT == 1) {
                    u16* C = (u16*)Cv;  // [M, 2*NN]
                    u16 hi = f2bf(v);
                    u16 lo = f2bf(v - bf2f(hi));
                    C[(size_t)grow * (2 * NN) + gc] = hi;
                    C[(size_t)grow * (2 * NN) + NN + gc] = lo;
                } else {
                    ((__half*)Cv)[(size_t)grow * NN + gc] = __float2half_rn(v);
                }
            }
        }
    }
}

// ---------------------------------------------------------------------------
// launch
// ---------------------------------------------------------------------------

extern "C" void kernel_launch(void* const* d_in, const int* in_sizes, int n_in,
                              void* d_out, int out_size, void* d_ws, size_t ws_size,
                              hipStream_t stream) {
    const float* x   = (const float*)d_in[0];
    const int*   ei  = (const int*)d_in[1];
    const float* wts = (const float*)d_in[2];
    const float* W1  = (const float*)d_in[3];
    const float* b1  = (const float*)d_in[4];
    const float* W2  = (const float*)d_in[5];
    const float* b2  = (const float*)d_in[6];
    const float* W3  = (const float*)d_in[7];
    const float* b3  = (const float*)d_in[8];
    float* out = (float*)d_out;
    const int* src = ei;
    const int* dst = ei + N_EDGES;

    float* bufA   = (float*)d_ws;                         // N*256 f32 worth
    float* bufB   = bufA + (size_t)N_NODES * D_HID;       // N*256 f32 worth
    float* ew     = bufB + (size_t)N_NODES * D_HID;       // [E]
    float* deg    = ew + N_EDGES;                         // [N] -> dinv
    int*   cnt    = (int*)(deg + N_NODES);                // [N]
    int*   fill   = cnt + N_NODES;                        // [N]
    int*   rowptr = fill + N_NODES;                       // [N+1]
    int2*  ecsr   = (int2*)(rowptr + (N_NODES + 2));      // [E] packed {src, norm}
    u16*   Wb1    = (u16*)(ecsr + N_EDGES);               // [256*256]
    u16*   Wb2    = Wb1 + 256 * 256;                      // [256*512]
    u16*   Wb3    = Wb2 + 256 * 512;                      // [128*512]

    hipMemsetAsync(deg, 0, sizeof(float) * N_NODES + sizeof(int) * 2 * N_NODES, stream);

    int ethreads = 256;
    int eblocks = (N_EDGES + ethreads - 1) / ethreads;
    k_edge_prep<<<eblocks, ethreads, 0, stream>>>(src, dst, wts, ew, deg, cnt);
    k_dinv<<<(N_NODES + 255) / 256, 256, 0, stream>>>(deg);
    k_scan<<<1, 1024, 0, stream>>>(cnt, rowptr);
    k_fill<<<eblocks, ethreads, 0, stream>>>(src, dst, ew, deg, rowptr, fill, ecsr);
    k_wprep<<<(WPREP_TOTAL + 255) / 256, 256, 0, stream>>>(W1, W2, W3, Wb1, Wb2, Wb3);

    int aggBlocks = (N_NODES + 3) / 4;
    int gy = (N_NODES + 127) / 128;  // 391

    // L1: A1' = hilo(A.x) [N,256]bf16 ; h1 = relu(A1' @ W1' + b1) -> fp16 [N,256]
    k_agg<128, 0, 1, false><<<aggBlocks, 256, 0, stream>>>(x, rowptr, ecsr, deg, nullptr, bufA);
    {
        dim3 g(2, gy);
        k_gemm_bf<2, true, true><<<g, 256, 0, stream>>>((const u16*)bufA, Wb1, b1, bufB,
                                                        N_NODES, D_IN, D_HID);
    }
    // L2: A2' = hilo(A.h1fp16) [N,512]bf16 ; h2hl = hilo(relu(A2' @ W2' + b2)) [N,512]bf16
    k_agg<256, 1, 1, false><<<aggBlocks, 256, 0, stream>>>(bufB, rowptr, ecsr, deg, nullptr, bufA);
    {
        dim3 g(2, gy);
        k_gemm_bf<1, true, true><<<g, 256, 0, stream>>>((const u16*)bufA, Wb2, b2, bufB,
                                                        N_NODES, D_HID, D_HID);
    }
    // L3: y3 = h2hl @ W3' -> fp16 [N,128] ; out = A.y3 + b3 (f32)
    {
        dim3 g(1, gy);
        k_gemm_bf<2, false, false><<<g, 256, 0, stream>>>((const u16*)bufB, Wb3, nullptr, bufA,
                                                          N_NODES, D_HID, D_OUT);
    }
    k_agg<128, 1, 0, true><<<aggBlocks, 256, 0, stream>>>(bufA, rowptr, ecsr, deg, b3, out);
}

// Round 7
// 440.875 us; speedup vs baseline: 1.7650x; 1.1553x over previous
//
#include <hip/hip_runtime.h>
#include <hip/hip_fp16.h>
#include <math.h>

#define N_NODES 50000
#define N_EDGES 600000
#define D_IN    128
#define D_HID   256
#define D_OUT   128
#define NB_SCAN ((N_NODES + 255) / 256)   // 196

typedef unsigned short u16;
typedef __attribute__((ext_vector_type(8))) short bf16x8;
typedef __attribute__((ext_vector_type(4))) float f32x4;

__device__ __forceinline__ u16 f2bf(float x) {
    unsigned int u = __float_as_uint(x);
    unsigned int r = (u + 0x7fffu + ((u >> 16) & 1u)) >> 16;
    return (u16)r;
}
__device__ __forceinline__ float bf2f(u16 h) {
    return __uint_as_float(((unsigned int)h) << 16);
}
__device__ __forceinline__ float2 h2f2(unsigned int raw) {
    __half2 h = *reinterpret_cast<__half2*>(&raw);
    return __half22float2(h);
}

// ---------------------------------------------------------------------------
// Setup: softplus, degree, dinv, CSR (packed {src, norm} records)
// ---------------------------------------------------------------------------

__global__ void k_edge_prep(const int* __restrict__ src, const int* __restrict__ dst,
                            const float* __restrict__ w, float* __restrict__ ew,
                            float* __restrict__ deg, int* __restrict__ cnt) {
    int e = blockIdx.x * blockDim.x + threadIdx.x;
    if (e >= N_EDGES) return;
    float x = w[e];
    float sp = fmaxf(x, 0.f) + log1pf(expf(-fabsf(x)));
    ew[e] = sp;
    int d = dst[e];
    atomicAdd(&deg[d], sp);
    atomicAdd(&cnt[d], 1);
    (void)src;
}

__global__ void k_dinv(float* __restrict__ deg) {
    int n = blockIdx.x * blockDim.x + threadIdx.x;
    if (n >= N_NODES) return;
    deg[n] = rsqrtf(deg[n] + 1.0f);
}

// ---- two-level scan: block-local excl scan + block totals ----
__global__ void k_scan1(const int* __restrict__ cnt, int* __restrict__ rowptr,
                        int* __restrict__ bsum) {
    __shared__ int s[256];
    int b = blockIdx.x, t = threadIdx.x;
    int i = b * 256 + t;
    int v = (i < N_NODES) ? cnt[i] : 0;
    s[t] = v;
    __syncthreads();
    for (int off = 1; off < 256; off <<= 1) {
        int u = (t >= off) ? s[t - off] : 0;
        __syncthreads();
        s[t] += u;
        __syncthreads();
    }
    if (i < N_NODES) rowptr[i] = s[t] - v;   // block-local exclusive
    if (t == 255) bsum[b] = s[255];          // block total
}

__global__ void k_scan2(const int* __restrict__ bsum, int* __restrict__ boff) {
    __shared__ int s[256];
    int t = threadIdx.x;
    int v = (t < NB_SCAN) ? bsum[t] : 0;
    s[t] = v;
    __syncthreads();
    for (int off = 1; off < 256; off <<= 1) {
        int u = (t >= off) ? s[t - off] : 0;
        __syncthreads();
        s[t] += u;
        __syncthreads();
    }
    if (t < NB_SCAN) boff[t] = s[t] - v;     // exclusive block offsets
    if (t == 255) boff[NB_SCAN] = s[255];    // grand total
}

__global__ void k_scan3(int* __restrict__ rowptr, const int* __restrict__ boff) {
    int b = blockIdx.x, t = threadIdx.x;
    int i = b * 256 + t;
    if (i < N_NODES) rowptr[i] += boff[b];
    if (i == 0) rowptr[N_NODES] = boff[NB_SCAN];
}

__global__ void k_fill(const int* __restrict__ src, const int* __restrict__ dst,
                       const float* __restrict__ ew, const float* __restrict__ dinv,
                       const int* __restrict__ rowptr, int* __restrict__ fill,
                       int2* __restrict__ ecsr) {
    int e = blockIdx.x * blockDim.x + threadIdx.x;
    if (e >= N_EDGES) return;
    int d = dst[e];
    int s = src[e];
    int pos = rowptr[d] + atomicAdd(&fill[d], 1);
    float w = dinv[s] * ew[e] * dinv[d];
    ecsr[pos] = make_int2(s, __float_as_int(w));
}

// ---------------------------------------------------------------------------
// Weight prep: W[K,N] f32 -> Wt[N, 2K] bf16 (hi plane cols 0..K-1, lo K..2K-1)
// ---------------------------------------------------------------------------

#define WPREP_TOTAL 131072

__global__ void k_wprep(const float* __restrict__ W1, const float* __restrict__ W2,
                        const float* __restrict__ W3,
                        u16* __restrict__ B1, u16* __restrict__ B2, u16* __restrict__ B3) {
    int idx = blockIdx.x * blockDim.x + threadIdx.x;
    const float* W; u16* B; int K, N, base;
    if (idx < 32768)       { W = W1; B = B1; K = 128; N = 256; base = 0; }
    else if (idx < 98304)  { W = W2; B = B2; K = 256; N = 256; base = 32768; }
    else if (idx < 131072) { W = W3; B = B3; K = 256; N = 128; base = 98304; }
    else return;
    int p = idx - base;
    int n = p % N, k = p / N;
    float x = W[(size_t)k * N + n];
    u16 hi = f2bf(x);
    u16 lo = f2bf(x - bf2f(hi));
    B[(size_t)n * (2 * K) + k] = hi;
    B[(size_t)n * (2 * K) + K + k] = lo;
}

// ---------------------------------------------------------------------------
// Aggregation. INF: 0 = f32 rows, 1 = fp16 rows. OUTM: 0 = f32 (+bias),
// 1 = bf16 hi/lo [N, 2D]. One wave per node, 4-deep gather pipeline.
// ---------------------------------------------------------------------------

template <int D, int INF, int OUTM, bool BIAS>
__global__ __launch_bounds__(256) void k_agg(const void* __restrict__ inv,
                                             const int* __restrict__ rowptr,
                                             const int2* __restrict__ ecsr,
                                             const float* __restrict__ dinv,
                                             const float* __restrict__ bias,
                                             void* __restrict__ outv) {
    int node = blockIdx.x * 4 + (threadIdx.x >> 6);
    int lane = threadIdx.x & 63;
    if (node >= N_NODES) return;
    float dn = dinv[node];
    float dd = dn * dn;
    int beg = rowptr[node], end = rowptr[node + 1];

    if (D == 256) {
        const float* inf = (const float*)inv;
        const u16* inh = (const u16*)inv;
        float sx, sy, sz, sw;
        if (INF == 0) {
            float4 sv = *(reinterpret_cast<const float4*>(inf + (size_t)node * D) + lane);
            sx = sv.x; sy = sv.y; sz = sv.z; sw = sv.w;
        } else {
            uint2 raw = *reinterpret_cast<const uint2*>(inh + (size_t)node * D + lane * 4);
            float2 f01 = h2f2(raw.x), f23 = h2f2(raw.y);
            sx = f01.x; sy = f01.y; sz = f23.x; sw = f23.y;
        }
        float ax = dd * sx, ay = dd * sy, az = dd * sz, aw = dd * sw;
        int p = beg;
        for (; p + 4 <= end; p += 4) {
            int2 e0 = ecsr[p], e1 = ecsr[p + 1], e2 = ecsr[p + 2], e3 = ecsr[p + 3];
            float w0 = __int_as_float(e0.y), w1 = __int_as_float(e1.y);
            float w2 = __int_as_float(e2.y), w3 = __int_as_float(e3.y);
            if (INF == 0) {
                float4 r0 = *(reinterpret_cast<const float4*>(inf + (size_t)e0.x * D) + lane);
                float4 r1 = *(reinterpret_cast<const float4*>(inf + (size_t)e1.x * D) + lane);
                float4 r2 = *(reinterpret_cast<const float4*>(inf + (size_t)e2.x * D) + lane);
                float4 r3 = *(reinterpret_cast<const float4*>(inf + (size_t)e3.x * D) + lane);
                ax += w0 * r0.x; ay += w0 * r0.y; az += w0 * r0.z; aw += w0 * r0.w;
                ax += w1 * r1.x; ay += w1 * r1.y; az += w1 * r1.z; aw += w1 * r1.w;
                ax += w2 * r2.x; ay += w2 * r2.y; az += w2 * r2.z; aw += w2 * r2.w;
                ax += w3 * r3.x; ay += w3 * r3.y; az += w3 * r3.z; aw += w3 * r3.w;
            } else {
                uint2 q0 = *reinterpret_cast<const uint2*>(inh + (size_t)e0.x * D + lane * 4);
                uint2 q1 = *reinterpret_cast<const uint2*>(inh + (size_t)e1.x * D + lane * 4);
                uint2 q2 = *reinterpret_cast<const uint2*>(inh + (size_t)e2.x * D + lane * 4);
                uint2 q3 = *reinterpret_cast<const uint2*>(inh + (size_t)e3.x * D + lane * 4);
                float2 a0 = h2f2(q0.x), b0 = h2f2(q0.y);
                float2 a1 = h2f2(q1.x), b1 = h2f2(q1.y);
                float2 a2 = h2f2(q2.x), b2 = h2f2(q2.y);
                float2 a3 = h2f2(q3.x), b3 = h2f2(q3.y);
                ax += w0 * a0.x; ay += w0 * a0.y; az += w0 * b0.x; aw += w0 * b0.y;
                ax += w1 * a1.x; ay += w1 * a1.y; az += w1 * b1.x; aw += w1 * b1.y;
                ax += w2 * a2.x; ay += w2 * a2.y; az += w2 * b2.x; aw += w2 * b2.y;
                ax += w3 * a3.x; ay += w3 * a3.y; az += w3 * b3.x; aw += w3 * b3.y;
            }
        }
        for (; p < end; p++) {
            int2 e0 = ecsr[p];
            float w0 = __int_as_float(e0.y);
            if (INF == 0) {
                float4 r0 = *(reinterpret_cast<const float4*>(inf + (size_t)e0.x * D) + lane);
                ax += w0 * r0.x; ay += w0 * r0.y; az += w0 * r0.z; aw += w0 * r0.w;
            } else {
                uint2 q0 = *reinterpret_cast<const uint2*>(inh + (size_t)e0.x * D + lane * 4);
                float2 a0 = h2f2(q0.x), b0 = h2f2(q0.y);
                ax += w0 * a0.x; ay += w0 * a0.y; az += w0 * b0.x; aw += w0 * b0.y;
            }
        }
        if (OUTM == 0) {
            float* out = (float*)outv;
            if (BIAS) {
                float4 b = *(reinterpret_cast<const float4*>(bias) + lane);
                ax += b.x; ay += b.y; az += b.z; aw += b.w;
            }
            float4 res; res.x = ax; res.y = ay; res.z = az; res.w = aw;
            *(reinterpret_cast<float4*>(out + (size_t)node * D) + lane) = res;
        } else {
            u16* out = (u16*)outv;  // [N, 512]
            u16 h0 = f2bf(ax), h1 = f2bf(ay), h2 = f2bf(az), h3 = f2bf(aw);
            ushort4 hv; hv.x = h0; hv.y = h1; hv.z = h2; hv.w = h3;
            ushort4 lv;
            lv.x = f2bf(ax - bf2f(h0)); lv.y = f2bf(ay - bf2f(h1));
            lv.z = f2bf(az - bf2f(h2)); lv.w = f2bf(aw - bf2f(h3));
            *(reinterpret_cast<ushort4*>(out + (size_t)node * 512) + lane) = hv;
            *(reinterpret_cast<ushort4*>(out + (size_t)node * 512 + 256) + lane) = lv;
        }
    } else {  // D == 128
        const float* inf = (const float*)inv;
        const u16* inh = (const u16*)inv;
        float sx, sy;
        if (INF == 0) {
            float2 sv = *(reinterpret_cast<const float2*>(inf + (size_t)node * D) + lane);
            sx = sv.x; sy = sv.y;
        } else {
            unsigned int raw = *reinterpret_cast<const unsigned int*>(inh + (size_t)node * D + lane * 2);
            float2 f = h2f2(raw);
            sx = f.x; sy = f.y;
        }
        float ax = dd * sx, ay = dd * sy;
        int p = beg;
        for (; p + 4 <= end; p += 4) {
            int2 e0 = ecsr[p], e1 = ecsr[p + 1], e2 = ecsr[p + 2], e3 = ecsr[p + 3];
            float w0 = __int_as_float(e0.y), w1 = __int_as_float(e1.y);
            float w2 = __int_as_float(e2.y), w3 = __int_as_float(e3.y);
            if (INF == 0) {
                float2 r0 = *(reinterpret_cast<const float2*>(inf + (size_t)e0.x * D) + lane);
                float2 r1 = *(reinterpret_cast<const float2*>(inf + (size_t)e1.x * D) + lane);
                float2 r2 = *(reinterpret_cast<const float2*>(inf + (size_t)e2.x * D) + lane);
                float2 r3 = *(reinterpret_cast<const float2*>(inf + (size_t)e3.x * D) + lane);
                ax += w0 * r0.x; ay += w0 * r0.y;
                ax += w1 * r1.x; ay += w1 * r1.y;
                ax += w2 * r2.x; ay += w2 * r2.y;
                ax += w3 * r3.x; ay += w3 * r3.y;
            } else {
                unsigned int q0 = *reinterpret_cast<const unsigned int*>(inh + (size_t)e0.x * D + lane * 2);
                unsigned int q1 = *reinterpret_cast<const unsigned int*>(inh + (size_t)e1.x * D + lane * 2);
                unsigned int q2 = *reinterpret_cast<const unsigned int*>(inh + (size_t)e2.x * D + lane * 2);
                unsigned int q3 = *reinterpret_cast<const unsigned int*>(inh + (size_t)e3.x * D + lane * 2);
                float2 f0 = h2f2(q0), f1 = h2f2(q1), f2 = h2f2(q2), f3 = h2f2(q3);
                ax += w0 * f0.x; ay += w0 * f0.y;
                ax += w1 * f1.x; ay += w1 * f1.y;
                ax += w2 * f2.x; ay += w2 * f2.y;
                ax += w3 * f3.x; ay += w3 * f3.y;
            }
        }
        for (; p < end; p++) {
            int2 e0 = ecsr[p];
            float w0 = __int_as_float(e0.y);
            if (INF == 0) {
                float2 r0 = *(reinterpret_cast<const float2*>(inf + (size_t)e0.x * D) + lane);
                ax += w0 * r0.x; ay += w0 * r0.y;
            } else {
                unsigned int q0 = *reinterpret_cast<const unsigned int*>(inh + (size_t)e0.x * D + lane * 2);
                float2 f0 = h2f2(q0);
                ax += w0 * f0.x; ay += w0 * f0.y;
            }
        }
        if (OUTM == 0) {
            float* out = (float*)outv;
            if (BIAS) {
                float2 b = *(reinterpret_cast<const float2*>(bias) + lane);
                ax += b.x; ay += b.y;
            }
            float2 res; res.x = ax; res.y = ay;
            *(reinterpret_cast<float2*>(out + (size_t)node * D) + lane) = res;
        } else {
            u16* out = (u16*)outv;  // [N, 256]
            u16 h0 = f2bf(ax), h1 = f2bf(ay);
            ushort2 hv; hv.x = h0; hv.y = h1;
            ushort2 lv; lv.x = f2bf(ax - bf2f(h0)); lv.y = f2bf(ay - bf2f(h1));
            *(reinterpret_cast<ushort2*>(out + (size_t)node * 256) + lane) = hv;
            *(reinterpret_cast<ushort2*>(out + (size_t)node * 256 + 128) + lane) = lv;
        }
    }
}

// ---------------------------------------------------------------------------
// Split-bf16 MFMA GEMM. OUT: 0 = f32, 1 = bf16 hi/lo [M,2NN], 2 = fp16 [M,NN].
// ---------------------------------------------------------------------------

template <int OUT, bool BIAS, bool RELU>
__global__ __launch_bounds__(256) void k_gemm_bf(const u16* __restrict__ Ap,
                                                 const u16* __restrict__ Bp,
                                                 const float* __restrict__ bias,
                                                 void* __restrict__ Cv,
                                                 int M, int K, int NN) {
    const int KP2 = 2 * K;
    __shared__ u16 As[8 * 512];
    __shared__ u16 Bs[8 * 512];
    int tid = threadIdx.x;
    int bm = blockIdx.y * 128;
    int bn = blockIdx.x * 128;
    int l = tid & 63;
    int w = tid >> 6;
    int wr = w >> 1, wc = w & 1;

    f32x4 zero = {0.f, 0.f, 0.f, 0.f};
    f32x4 acc[4][4];
    #pragma unroll
    for (int i = 0; i < 4; i++)
        #pragma unroll
        for (int j = 0; j < 4; j++) acc[i][j] = zero;

    int sm = tid >> 2;
    int soct = tid & 3;

    for (int k0 = 0; k0 < 3 * K; k0 += 32) {
        int ak = (k0 < 2 * K) ? k0 : k0 - 2 * K;
        int bk = (k0 < K) ? k0 : k0 - K;
        #pragma unroll
        for (int q = 0; q < 2; q++) {
            int r = sm + q * 64;
            int lds = (r >> 4) * 512 + ((r & 15) + soct * 16) * 8;
            int gr = bm + r;
            uint4 va = make_uint4(0u, 0u, 0u, 0u);
            if (gr < M)
                va = *reinterpret_cast<const uint4*>(Ap + (size_t)gr * KP2 + ak + soct * 8);
            *reinterpret_cast<uint4*>(&As[lds]) = va;
            uint4 vb = *reinterpret_cast<const uint4*>(Bp + (size_t)(bn + r) * KP2 + bk + soct * 8);
            *reinterpret_cast<uint4*>(&Bs[lds]) = vb;
        }
        __syncthreads();
        bf16x8 a[4], b[4];
        #pragma unroll
        for (int i = 0; i < 4; i++)
            a[i] = *reinterpret_cast<const bf16x8*>(&As[(wr * 4 + i) * 512 + l * 8]);
        #pragma unroll
        for (int j = 0; j < 4; j++)
            b[j] = *reinterpret_cast<const bf16x8*>(&Bs[(wc * 4 + j) * 512 + l * 8]);
        #pragma unroll
        for (int i = 0; i < 4; i++)
            #pragma unroll
            for (int j = 0; j < 4; j++)
                acc[i][j] = __builtin_amdgcn_mfma_f32_16x16x32_bf16(a[i], b[j], acc[i][j], 0, 0, 0);
        __syncthreads();
    }

    int cl = l & 15;
    int rq = (l >> 4) * 4;
    float bv[4];
    #pragma unroll
    for (int j = 0; j < 4; j++) {
        int gc = bn + wc * 64 + j * 16 + cl;
        bv[j] = BIAS ? bias[gc] : 0.f;
    }
    #pragma unroll
    for (int i = 0; i < 4; i++) {
        #pragma unroll
        for (int r = 0; r < 4; r++) {
            int grow = bm + wr * 64 + i * 16 + rq + r;
            if (grow >= M) continue;
            #pragma unroll
            for (int j = 0; j < 4; j++) {
                int gc = bn + wc * 64 + j * 16 + cl;
                float v = acc[i][j][r];
                if (BIAS) v += bv[j];
                if (RELU) v = fmaxf(v, 0.f);
                if (OUT == 0) {
                    ((float*)Cv)[(size_t)grow * NN + gc] = v;
                } else if (OUT == 1) {
                    u16* C = (u16*)Cv;  // [M, 2*NN]
                    u16 hi = f2bf(v);
                    u16 lo = f2bf(v - bf2f(hi));
                    C[(size_t)grow * (2 * NN) + gc] = hi;
                    C[(size_t)grow * (2 * NN) + NN + gc] = lo;
                } else {
                    ((__half*)Cv)[(size_t)grow * NN + gc] = __float2half_rn(v);
                }
            }
        }
    }
}

// ---------------------------------------------------------------------------
// launch
// ---------------------------------------------------------------------------

extern "C" void kernel_launch(void* const* d_in, const int* in_sizes, int n_in,
                              void* d_out, int out_size, void* d_ws, size_t ws_size,
                              hipStream_t stream) {
    const float* x   = (const float*)d_in[0];
    const int*   ei  = (const int*)d_in[1];
    const float* wts = (const float*)d_in[2];
    const float* W1  = (const float*)d_in[3];
    const float* b1  = (const float*)d_in[4];
    const float* W2  = (const float*)d_in[5];
    const float* b2  = (const float*)d_in[6];
    const float* W3  = (const float*)d_in[7];
    const float* b3  = (const float*)d_in[8];
    float* out = (float*)d_out;
    const int* src = ei;
    const int* dst = ei + N_EDGES;

    float* bufA   = (float*)d_ws;                         // N*256 f32 worth
    float* bufB   = bufA + (size_t)N_NODES * D_HID;       // N*256 f32 worth
    float* ew     = bufB + (size_t)N_NODES * D_HID;       // [E]
    float* deg    = ew + N_EDGES;                         // [N] -> dinv
    int*   cnt    = (int*)(deg + N_NODES);                // [N]
    int*   fill   = cnt + N_NODES;                        // [N]
    int*   rowptr = fill + N_NODES;                       // [N+1]
    int2*  ecsr   = (int2*)(rowptr + (N_NODES + 2));      // [E] packed {src, norm}
    u16*   Wb1    = (u16*)(ecsr + N_EDGES);               // [256*256]
    u16*   Wb2    = Wb1 + 256 * 256;                      // [256*512]
    u16*   Wb3    = Wb2 + 256 * 512;                      // [128*512]
    int*   bsum   = (int*)(Wb3 + 128 * 512);              // [NB_SCAN]
    int*   boff   = bsum + NB_SCAN;                       // [NB_SCAN+1]

    hipMemsetAsync(deg, 0, sizeof(float) * N_NODES + sizeof(int) * 2 * N_NODES, stream);

    int ethreads = 256;
    int eblocks = (N_EDGES + ethreads - 1) / ethreads;
    k_edge_prep<<<eblocks, ethreads, 0, stream>>>(src, dst, wts, ew, deg, cnt);
    k_dinv<<<(N_NODES + 255) / 256, 256, 0, stream>>>(deg);
    k_scan1<<<NB_SCAN, 256, 0, stream>>>(cnt, rowptr, bsum);
    k_scan2<<<1, 256, 0, stream>>>(bsum, boff);
    k_scan3<<<NB_SCAN, 256, 0, stream>>>(rowptr, boff);
    k_fill<<<eblocks, ethreads, 0, stream>>>(src, dst, ew, deg, rowptr, fill, ecsr);
    k_wprep<<<(WPREP_TOTAL + 255) / 256, 256, 0, stream>>>(W1, W2, W3, Wb1, Wb2, Wb3);

    int aggBlocks = (N_NODES + 3) / 4;
    int gy = (N_NODES + 127) / 128;  // 391

    // L1: A1' = hilo(A.x) [N,256]bf16 ; h1 = relu(A1' @ W1' + b1) -> fp16 [N,256]
    k_agg<128, 0, 1, false><<<aggBlocks, 256, 0, stream>>>(x, rowptr, ecsr, deg, nullptr, bufA);
    {
        dim3 g(2, gy);
        k_gemm_bf<2, true, true><<<g, 256, 0, stream>>>((const u16*)bufA, Wb1, b1, bufB,
                                                        N_NODES, D_IN, D_HID);
    }
    // L2: A2' = hilo(A.h1fp16) [N,512]bf16 ; h2hl = hilo(relu(A2' @ W2' + b2)) [N,512]bf16
    k_agg<256, 1, 1, false><<<aggBlocks, 256, 0, stream>>>(bufB, rowptr, ecsr, deg, nullptr, bufA);
    {
        dim3 g(2, gy);
        k_gemm_bf<1, true, true><<<g, 256, 0, stream>>>((const u16*)bufA, Wb2, b2, bufB,
                                                        N_NODES, D_HID, D_HID);
    }
    // L3: y3 = h2hl @ W3' -> fp16 [N,128] ; out = A.y3 + b3 (f32)
    {
        dim3 g(1, gy);
        k_gemm_bf<2, false, false><<<g, 256, 0, stream>>>((const u16*)bufB, Wb3, nullptr, bufA,
                                                          N_NODES, D_HID, D_OUT);
    }
    k_agg<128, 1, 0, true><<<aggBlocks, 256, 0, stream>>>(bufA, rowptr, ecsr, deg, b3, out);
}

// Round 8
// 384.238 us; speedup vs baseline: 2.0252x; 1.1474x over previous
//
#include <hip/hip_runtime.h>
#include <hip/hip_fp16.h>
#include <math.h>

#define N_NODES 50000
#define N_EDGES 600000
#define D_IN    128
#define D_HID   256
#define D_OUT   128
#define NB_SCAN ((N_NODES + 255) / 256)   // 196

typedef unsigned short u16;
typedef __attribute__((ext_vector_type(8))) _Float16 f16x8;
typedef __attribute__((ext_vector_type(4))) float f32x4;

__device__ __forceinline__ u16 f2h(float x) {
    __half h = __float2half_rn(x);
    return *reinterpret_cast<u16*>(&h);
}
__device__ __forceinline__ float h2f(u16 h) {
    __half hh = *reinterpret_cast<__half*>(&h);
    return __half2float(hh);
}
__device__ __forceinline__ float2 h2f2(unsigned int raw) {
    __half2 h = *reinterpret_cast<__half2*>(&raw);
    return __half22float2(h);
}

// ---------------------------------------------------------------------------
// Setup: softplus, degree, dinv, CSR (packed {src, norm} records)
// ---------------------------------------------------------------------------

__global__ void k_edge_prep(const int* __restrict__ src, const int* __restrict__ dst,
                            const float* __restrict__ w, float* __restrict__ ew,
                            float* __restrict__ deg, int* __restrict__ cnt) {
    int e = blockIdx.x * blockDim.x + threadIdx.x;
    if (e >= N_EDGES) return;
    float x = w[e];
    float sp = fmaxf(x, 0.f) + log1pf(expf(-fabsf(x)));
    ew[e] = sp;
    int d = dst[e];
    atomicAdd(&deg[d], sp);
    atomicAdd(&cnt[d], 1);
    (void)src;
}

__global__ void k_dinv(float* __restrict__ deg) {
    int n = blockIdx.x * blockDim.x + threadIdx.x;
    if (n >= N_NODES) return;
    deg[n] = rsqrtf(deg[n] + 1.0f);
}

__global__ void k_scan1(const int* __restrict__ cnt, int* __restrict__ rowptr,
                        int* __restrict__ bsum) {
    __shared__ int s[256];
    int b = blockIdx.x, t = threadIdx.x;
    int i = b * 256 + t;
    int v = (i < N_NODES) ? cnt[i] : 0;
    s[t] = v;
    __syncthreads();
    for (int off = 1; off < 256; off <<= 1) {
        int u = (t >= off) ? s[t - off] : 0;
        __syncthreads();
        s[t] += u;
        __syncthreads();
    }
    if (i < N_NODES) rowptr[i] = s[t] - v;
    if (t == 255) bsum[b] = s[255];
}

__global__ void k_scan2(const int* __restrict__ bsum, int* __restrict__ boff) {
    __shared__ int s[256];
    int t = threadIdx.x;
    int v = (t < NB_SCAN) ? bsum[t] : 0;
    s[t] = v;
    __syncthreads();
    for (int off = 1; off < 256; off <<= 1) {
        int u = (t >= off) ? s[t - off] : 0;
        __syncthreads();
        s[t] += u;
        __syncthreads();
    }
    if (t < NB_SCAN) boff[t] = s[t] - v;
    if (t == 255) boff[NB_SCAN] = s[255];
}

__global__ void k_scan3(int* __restrict__ rowptr, const int* __restrict__ boff) {
    int b = blockIdx.x, t = threadIdx.x;
    int i = b * 256 + t;
    if (i < N_NODES) rowptr[i] += boff[b];
    if (i == 0) rowptr[N_NODES] = boff[NB_SCAN];
}

__global__ void k_fill(const int* __restrict__ src, const int* __restrict__ dst,
                       const float* __restrict__ ew, const float* __restrict__ dinv,
                       const int* __restrict__ rowptr, int* __restrict__ fill,
                       int2* __restrict__ ecsr) {
    int e = blockIdx.x * blockDim.x + threadIdx.x;
    if (e >= N_EDGES) return;
    int d = dst[e];
    int s = src[e];
    int pos = rowptr[d] + atomicAdd(&fill[d], 1);
    float w = dinv[s] * ew[e] * dinv[d];
    ecsr[pos] = make_int2(s, __float_as_int(w));
}

// ---------------------------------------------------------------------------
// Weight prep: W[K,N] f32 -> Wt[N, 2K] fp16 (hi plane 0..K-1, lo plane K..2K-1)
// ---------------------------------------------------------------------------

#define WPREP_TOTAL 131072

__global__ void k_wprep(const float* __restrict__ W1, const float* __restrict__ W2,
                        const float* __restrict__ W3,
                        u16* __restrict__ B1, u16* __restrict__ B2, u16* __restrict__ B3) {
    int idx = blockIdx.x * blockDim.x + threadIdx.x;
    const float* W; u16* B; int K, N, base;
    if (idx < 32768)       { W = W1; B = B1; K = 128; N = 256; base = 0; }
    else if (idx < 98304)  { W = W2; B = B2; K = 256; N = 256; base = 32768; }
    else if (idx < 131072) { W = W3; B = B3; K = 256; N = 128; base = 98304; }
    else return;
    int p = idx - base;
    int n = p % N, k = p / N;
    float x = W[(size_t)k * N + n];
    u16 hi = f2h(x);
    u16 lo = f2h(x - h2f(hi));
    B[(size_t)n * (2 * K) + k] = hi;
    B[(size_t)n * (2 * K) + K + k] = lo;
}

// ---------------------------------------------------------------------------
// Aggregation. INF: 0 = f32 rows, 1 = fp16 rows. OUTM: 0 = f32 (+bias),
// 1 = fp16 [N, D]. One wave per node, 4-deep gather pipeline.
// ---------------------------------------------------------------------------

template <int D, int INF, int OUTM, bool BIAS>
__global__ __launch_bounds__(256) void k_agg(const void* __restrict__ inv,
                                             const int* __restrict__ rowptr,
                                             const int2* __restrict__ ecsr,
                                             const float* __restrict__ dinv,
                                             const float* __restrict__ bias,
                                             void* __restrict__ outv) {
    int node = blockIdx.x * 4 + (threadIdx.x >> 6);
    int lane = threadIdx.x & 63;
    if (node >= N_NODES) return;
    float dn = dinv[node];
    float dd = dn * dn;
    int beg = rowptr[node], end = rowptr[node + 1];

    if (D == 256) {
        const float* inf = (const float*)inv;
        const u16* inh = (const u16*)inv;
        float sx, sy, sz, sw;
        if (INF == 0) {
            float4 sv = *(reinterpret_cast<const float4*>(inf + (size_t)node * D) + lane);
            sx = sv.x; sy = sv.y; sz = sv.z; sw = sv.w;
        } else {
            uint2 raw = *reinterpret_cast<const uint2*>(inh + (size_t)node * D + lane * 4);
            float2 f01 = h2f2(raw.x), f23 = h2f2(raw.y);
            sx = f01.x; sy = f01.y; sz = f23.x; sw = f23.y;
        }
        float ax = dd * sx, ay = dd * sy, az = dd * sz, aw = dd * sw;
        int p = beg;
        for (; p + 4 <= end; p += 4) {
            int2 e0 = ecsr[p], e1 = ecsr[p + 1], e2 = ecsr[p + 2], e3 = ecsr[p + 3];
            float w0 = __int_as_float(e0.y), w1 = __int_as_float(e1.y);
            float w2 = __int_as_float(e2.y), w3 = __int_as_float(e3.y);
            if (INF == 0) {
                float4 r0 = *(reinterpret_cast<const float4*>(inf + (size_t)e0.x * D) + lane);
                float4 r1 = *(reinterpret_cast<const float4*>(inf + (size_t)e1.x * D) + lane);
                float4 r2 = *(reinterpret_cast<const float4*>(inf + (size_t)e2.x * D) + lane);
                float4 r3 = *(reinterpret_cast<const float4*>(inf + (size_t)e3.x * D) + lane);
                ax += w0 * r0.x; ay += w0 * r0.y; az += w0 * r0.z; aw += w0 * r0.w;
                ax += w1 * r1.x; ay += w1 * r1.y; az += w1 * r1.z; aw += w1 * r1.w;
                ax += w2 * r2.x; ay += w2 * r2.y; az += w2 * r2.z; aw += w2 * r2.w;
                ax += w3 * r3.x; ay += w3 * r3.y; az += w3 * r3.z; aw += w3 * r3.w;
            } else {
                uint2 q0 = *reinterpret_cast<const uint2*>(inh + (size_t)e0.x * D + lane * 4);
                uint2 q1 = *reinterpret_cast<const uint2*>(inh + (size_t)e1.x * D + lane * 4);
                uint2 q2 = *reinterpret_cast<const uint2*>(inh + (size_t)e2.x * D + lane * 4);
                uint2 q3 = *reinterpret_cast<const uint2*>(inh + (size_t)e3.x * D + lane * 4);
                float2 a0 = h2f2(q0.x), b0 = h2f2(q0.y);
                float2 a1 = h2f2(q1.x), b1 = h2f2(q1.y);
                float2 a2 = h2f2(q2.x), b2 = h2f2(q2.y);
                float2 a3 = h2f2(q3.x), b3 = h2f2(q3.y);
                ax += w0 * a0.x; ay += w0 * a0.y; az += w0 * b0.x; aw += w0 * b0.y;
                ax += w1 * a1.x; ay += w1 * a1.y; az += w1 * b1.x; aw += w1 * b1.y;
                ax += w2 * a2.x; ay += w2 * a2.y; az += w2 * b2.x; aw += w2 * b2.y;
                ax += w3 * a3.x; ay += w3 * a3.y; az += w3 * b3.x; aw += w3 * b3.y;
            }
        }
        for (; p < end; p++) {
            int2 e0 = ecsr[p];
            float w0 = __int_as_float(e0.y);
            if (INF == 0) {
                float4 r0 = *(reinterpret_cast<const float4*>(inf + (size_t)e0.x * D) + lane);
                ax += w0 * r0.x; ay += w0 * r0.y; az += w0 * r0.z; aw += w0 * r0.w;
            } else {
                uint2 q0 = *reinterpret_cast<const uint2*>(inh + (size_t)e0.x * D + lane * 4);
                float2 a0 = h2f2(q0.x), b0 = h2f2(q0.y);
                ax += w0 * a0.x; ay += w0 * a0.y; az += w0 * b0.x; aw += w0 * b0.y;
            }
        }
        if (OUTM == 0) {
            float* out = (float*)outv;
            if (BIAS) {
                float4 b = *(reinterpret_cast<const float4*>(bias) + lane);
                ax += b.x; ay += b.y; az += b.z; aw += b.w;
            }
            float4 res; res.x = ax; res.y = ay; res.z = az; res.w = aw;
            *(reinterpret_cast<float4*>(out + (size_t)node * D) + lane) = res;
        } else {
            u16* out = (u16*)outv;  // fp16 [N, 256]
            ushort4 hv;
            hv.x = f2h(ax); hv.y = f2h(ay); hv.z = f2h(az); hv.w = f2h(aw);
            *reinterpret_cast<ushort4*>(out + (size_t)node * D + lane * 4) = hv;
        }
    } else {  // D == 128
        const float* inf = (const float*)inv;
        const u16* inh = (const u16*)inv;
        float sx, sy;
        if (INF == 0) {
            float2 sv = *(reinterpret_cast<const float2*>(inf + (size_t)node * D) + lane);
            sx = sv.x; sy = sv.y;
        } else {
            unsigned int raw = *reinterpret_cast<const unsigned int*>(inh + (size_t)node * D + lane * 2);
            float2 f = h2f2(raw);
            sx = f.x; sy = f.y;
        }
        float ax = dd * sx, ay = dd * sy;
        int p = beg;
        for (; p + 4 <= end; p += 4) {
            int2 e0 = ecsr[p], e1 = ecsr[p + 1], e2 = ecsr[p + 2], e3 = ecsr[p + 3];
            float w0 = __int_as_float(e0.y), w1 = __int_as_float(e1.y);
            float w2 = __int_as_float(e2.y), w3 = __int_as_float(e3.y);
            if (INF == 0) {
                float2 r0 = *(reinterpret_cast<const float2*>(inf + (size_t)e0.x * D) + lane);
                float2 r1 = *(reinterpret_cast<const float2*>(inf + (size_t)e1.x * D) + lane);
                float2 r2 = *(reinterpret_cast<const float2*>(inf + (size_t)e2.x * D) + lane);
                float2 r3 = *(reinterpret_cast<const float2*>(inf + (size_t)e3.x * D) + lane);
                ax += w0 * r0.x; ay += w0 * r0.y;
                ax += w1 * r1.x; ay += w1 * r1.y;
                ax += w2 * r2.x; ay += w2 * r2.y;
                ax += w3 * r3.x; ay += w3 * r3.y;
            } else {
                unsigned int q0 = *reinterpret_cast<const unsigned int*>(inh + (size_t)e0.x * D + lane * 2);
                unsigned int q1 = *reinterpret_cast<const unsigned int*>(inh + (size_t)e1.x * D + lane * 2);
                unsigned int q2 = *reinterpret_cast<const unsigned int*>(inh + (size_t)e2.x * D + lane * 2);
                unsigned int q3 = *reinterpret_cast<const unsigned int*>(inh + (size_t)e3.x * D + lane * 2);
                float2 f0 = h2f2(q0), f1 = h2f2(q1), f2 = h2f2(q2), f3 = h2f2(q3);
                ax += w0 * f0.x; ay += w0 * f0.y;
                ax += w1 * f1.x; ay += w1 * f1.y;
                ax += w2 * f2.x; ay += w2 * f2.y;
                ax += w3 * f3.x; ay += w3 * f3.y;
            }
        }
        for (; p < end; p++) {
            int2 e0 = ecsr[p];
            float w0 = __int_as_float(e0.y);
            if (INF == 0) {
                float2 r0 = *(reinterpret_cast<const float2*>(inf + (size_t)e0.x * D) + lane);
                ax += w0 * r0.x; ay += w0 * r0.y;
            } else {
                unsigned int q0 = *reinterpret_cast<const unsigned int*>(inh + (size_t)e0.x * D + lane * 2);
                float2 f0 = h2f2(q0);
                ax += w0 * f0.x; ay += w0 * f0.y;
            }
        }
        if (OUTM == 0) {
            float* out = (float*)outv;
            if (BIAS) {
                float2 b = *(reinterpret_cast<const float2*>(bias) + lane);
                ax += b.x; ay += b.y;
            }
            float2 res; res.x = ax; res.y = ay;
            *(reinterpret_cast<float2*>(out + (size_t)node * D) + lane) = res;
        } else {
            u16* out = (u16*)outv;  // fp16 [N, 128]
            ushort2 hv; hv.x = f2h(ax); hv.y = f2h(ay);
            *reinterpret_cast<ushort2*>(out + (size_t)node * D + lane * 2) = hv;
        }
    }
}

// ---------------------------------------------------------------------------
// fp16 MFMA GEMM with fp16-hilo weights.
// A [M,K] fp16 (single plane). B [NN,2K] fp16 (hi|lo planes, row n = W^T).
// C = A*Bh + A*Bl via mfma_f32_16x16x32_f16, K-loop over 32-chunks: A read 1.0x.
// LDS: group (16 rows x 32 k) = 544 u16 (octet stride 136 u16 = 272B, co-prime
// with 128B bank wrap -> staging writes spread banks). Fragment reads use the
// same padded addressing. OUT: 0 = f32 C[M,NN], 1 = fp16 C[M,NN].
// ---------------------------------------------------------------------------

template <int OUT, bool BIAS, bool RELU>
__global__ __launch_bounds__(256) void k_gemm_h(const u16* __restrict__ Ap,
                                                const u16* __restrict__ Bp,
                                                const float* __restrict__ bias,
                                                void* __restrict__ Cv,
                                                int M, int K, int NN) {
    const int KP2 = 2 * K;
    __shared__ u16 As[8 * 544];        // 8 groups
    __shared__ u16 Bs[2 * 8 * 544];    // 2 halves x 8 groups
    int tid = threadIdx.x;
    int bm = blockIdx.y * 128;
    int bn = blockIdx.x * 128;
    int l = tid & 63;
    int w = tid >> 6;
    int wr = w >> 1, wc = w & 1;

    f32x4 zero = {0.f, 0.f, 0.f, 0.f};
    f32x4 acc[4][4];
    #pragma unroll
    for (int i = 0; i < 4; i++)
        #pragma unroll
        for (int j = 0; j < 4; j++) acc[i][j] = zero;

    for (int k0 = 0; k0 < K; k0 += 32) {
        // ---- stage A: 128 rows x 32 k = 512 uint4, 2 per thread ----
        #pragma unroll
        for (int q = 0; q < 2; q++) {
            int idx = tid + q * 256;
            int r = idx >> 2, o = idx & 3;   // row 0..127, k-octet 0..3
            int gr = bm + r;
            uint4 va = make_uint4(0u, 0u, 0u, 0u);
            if (gr < M)
                va = *reinterpret_cast<const uint4*>(Ap + (size_t)gr * K + k0 + o * 8);
            *reinterpret_cast<uint4*>(&As[(r >> 4) * 544 + o * 136 + (r & 15) * 8]) = va;
        }
        // ---- stage B: 2 planes x 128 rows x 32 k = 1024 uint4, 4 per thread ----
        #pragma unroll
        for (int q = 0; q < 4; q++) {
            int idx = tid + q * 256;
            int r = idx >> 3, oct = idx & 7;  // row 0..127, oct 0..7
            int hf = oct >> 2, o = oct & 3;   // plane, k-octet
            uint4 vb = *reinterpret_cast<const uint4*>(
                Bp + (size_t)(bn + r) * KP2 + hf * K + k0 + o * 8);
            *reinterpret_cast<uint4*>(
                &Bs[hf * 4352 + (r >> 4) * 544 + o * 136 + (r & 15) * 8]) = vb;
        }
        __syncthreads();
        int fro = (l >> 4) * 136 + (l & 15) * 8;
        f16x8 a[4], bh[4], bl[4];
        #pragma unroll
        for (int i = 0; i < 4; i++)
            a[i] = *reinterpret_cast<const f16x8*>(&As[(wr * 4 + i) * 544 + fro]);
        #pragma unroll
        for (int j = 0; j < 4; j++) {
            bh[j] = *reinterpret_cast<const f16x8*>(&Bs[(wc * 4 + j) * 544 + fro]);
            bl[j] = *reinterpret_cast<const f16x8*>(&Bs[4352 + (wc * 4 + j) * 544 + fro]);
        }
        #pragma unroll
        for (int i = 0; i < 4; i++)
            #pragma unroll
            for (int j = 0; j < 4; j++) {
                acc[i][j] = __builtin_amdgcn_mfma_f32_16x16x32_f16(a[i], bh[j], acc[i][j], 0, 0, 0);
                acc[i][j] = __builtin_amdgcn_mfma_f32_16x16x32_f16(a[i], bl[j], acc[i][j], 0, 0, 0);
            }
        __syncthreads();
    }

    // epilogue: C/D layout col = lane&15, row = (lane>>4)*4 + reg
    int cl = l & 15;
    int rq = (l >> 4) * 4;
    float bv[4];
    #pragma unroll
    for (int j = 0; j < 4; j++) {
        int gc = bn + wc * 64 + j * 16 + cl;
        bv[j] = BIAS ? bias[gc] : 0.f;
    }
    #pragma unroll
    for (int i = 0; i < 4; i++) {
        #pragma unroll
        for (int r = 0; r < 4; r++) {
            int grow = bm + wr * 64 + i * 16 + rq + r;
            if (grow >= M) continue;
            #pragma unroll
            for (int j = 0; j < 4; j++) {
                int gc = bn + wc * 64 + j * 16 + cl;
                float v = acc[i][j][r];
                if (BIAS) v += bv[j];
                if (RELU) v = fmaxf(v, 0.f);
                if (OUT == 0) {
                    ((float*)Cv)[(size_t)grow * NN + gc] = v;
                } else {
                    ((u16*)Cv)[(size_t)grow * NN + gc] = f2h(v);
                }
            }
        }
    }
}

// ---------------------------------------------------------------------------
// launch
// ---------------------------------------------------------------------------

extern "C" void kernel_launch(void* const* d_in, const int* in_sizes, int n_in,
                              void* d_out, int out_size, void* d_ws, size_t ws_size,
                              hipStream_t stream) {
    const float* x   = (const float*)d_in[0];
    const int*   ei  = (const int*)d_in[1];
    const float* wts = (const float*)d_in[2];
    const float* W1  = (const float*)d_in[3];
    const float* b1  = (const float*)d_in[4];
    const float* W2  = (const float*)d_in[5];
    const float* b2  = (const float*)d_in[6];
    const float* W3  = (const float*)d_in[7];
    const float* b3  = (const float*)d_in[8];
    float* out = (float*)d_out;
    const int* src = ei;
    const int* dst = ei + N_EDGES;

    float* bufA   = (float*)d_ws;                         // fp16 [N,256] max
    float* bufB   = bufA + (size_t)N_NODES * D_HID;       // fp16 [N,256] max
    float* ew     = bufB + (size_t)N_NODES * D_HID;       // [E]
    float* deg    = ew + N_EDGES;                         // [N] -> dinv
    int*   cnt    = (int*)(deg + N_NODES);                // [N]
    int*   fill   = cnt + N_NODES;                        // [N]
    int*   rowptr = fill + N_NODES;                       // [N+1]
    int2*  ecsr   = (int2*)(rowptr + (N_NODES + 2));      // [E] packed {src, norm}
    u16*   Wb1    = (u16*)(ecsr + N_EDGES);               // [256*256]
    u16*   Wb2    = Wb1 + 256 * 256;                      // [256*512]
    u16*   Wb3    = Wb2 + 256 * 512;                      // [128*512]
    int*   bsum   = (int*)(Wb3 + 128 * 512);              // [NB_SCAN]
    int*   boff   = bsum + NB_SCAN;                       // [NB_SCAN+1]

    hipMemsetAsync(deg, 0, sizeof(float) * N_NODES + sizeof(int) * 2 * N_NODES, stream);

    int ethreads = 256;
    int eblocks = (N_EDGES + ethreads - 1) / ethreads;
    k_edge_prep<<<eblocks, ethreads, 0, stream>>>(src, dst, wts, ew, deg, cnt);
    k_dinv<<<(N_NODES + 255) / 256, 256, 0, stream>>>(deg);
    k_scan1<<<NB_SCAN, 256, 0, stream>>>(cnt, rowptr, bsum);
    k_scan2<<<1, 256, 0, stream>>>(bsum, boff);
    k_scan3<<<NB_SCAN, 256, 0, stream>>>(rowptr, boff);
    k_fill<<<eblocks, ethreads, 0, stream>>>(src, dst, ew, deg, rowptr, fill, ecsr);
    k_wprep<<<(WPREP_TOTAL + 255) / 256, 256, 0, stream>>>(W1, W2, W3, Wb1, Wb2, Wb3);

    int aggBlocks = (N_NODES + 3) / 4;
    int gy = (N_NODES + 127) / 128;  // 391

    // agg1: x (f32) -> bufA fp16 [N,128]
    k_agg<128, 0, 1, false><<<aggBlocks, 256, 0, stream>>>(x, rowptr, ecsr, deg, nullptr, bufA);
    // gemm1: h1 = relu(bufA @ W1 + b1) -> bufB fp16 [N,256]
    {
        dim3 g(2, gy);
        k_gemm_h<1, true, true><<<g, 256, 0, stream>>>((const u16*)bufA, Wb1, b1, bufB,
                                                       N_NODES, D_IN, D_HID);
    }
    // agg2: bufB fp16 -> bufA fp16 [N,256]
    k_agg<256, 1, 1, false><<<aggBlocks, 256, 0, stream>>>(bufB, rowptr, ecsr, deg, nullptr, bufA);
    // gemm2: h2 = relu(bufA @ W2 + b2) -> bufB fp16 [N,256]
    {
        dim3 g(2, gy);
        k_gemm_h<1, true, true><<<g, 256, 0, stream>>>((const u16*)bufA, Wb2, b2, bufB,
                                                       N_NODES, D_HID, D_HID);
    }
    // gemm3: y3 = bufB @ W3 -> bufA fp16 [N,128]
    {
        dim3 g(1, gy);
        k_gemm_h<1, false, false><<<g, 256, 0, stream>>>((const u16*)bufB, Wb3, nullptr, bufA,
                                                         N_NODES, D_HID, D_OUT);
    }
    // agg3: bufA fp16 -> out f32 + b3
    k_agg<128, 1, 0, true><<<aggBlocks, 256, 0, stream>>>(bufA, rowptr, ecsr, deg, b3, out);
}

// Round 9
// 346.651 us; speedup vs baseline: 2.2447x; 1.1084x over previous
//
#include <hip/hip_runtime.h>
#include <hip/hip_fp16.h>
#include <math.h>

#define N_NODES 50000
#define N_EDGES 600000
#define D_IN    128
#define D_HID   256
#define D_OUT   128
#define NB_SCAN ((N_NODES + 255) / 256)   // 196

typedef unsigned short u16;
typedef __attribute__((ext_vector_type(8))) _Float16 f16x8;
typedef __attribute__((ext_vector_type(4))) float f32x4;

__device__ __forceinline__ u16 f2h(float x) {
    __half h = __float2half_rn(x);
    return *reinterpret_cast<u16*>(&h);
}
__device__ __forceinline__ float h2f(u16 h) {
    __half hh = *reinterpret_cast<__half*>(&h);
    return __half2float(hh);
}
__device__ __forceinline__ float2 h2f2(unsigned int raw) {
    __half2 h = *reinterpret_cast<__half2*>(&raw);
    return __half22float2(h);
}

// ---------------------------------------------------------------------------
// Setup chain, one atomic per edge total:
//   k_hist:   rank[e] = atomicAdd(cnt[dst],1); ew[e] = softplus(w[e])
//   scans:    rowptr = exclusive_scan(cnt)
//   k_fill2:  ecsr[rowptr[d]+rank[e]] = {src, sp}          (NO atomic)
//   k_degdinv: per-node segment sum of sp -> dinv = rsqrt(deg+1)
//   k_norm:   per-node: ecsr.w = dinv[s]*sp*dinv[n]
// ---------------------------------------------------------------------------

__global__ void k_hist(const int* __restrict__ dst, const float* __restrict__ w,
                       float* __restrict__ ew, int* __restrict__ rank,
                       int* __restrict__ cnt) {
    int e = blockIdx.x * blockDim.x + threadIdx.x;
    if (e >= N_EDGES) return;
    float x = w[e];
    ew[e] = fmaxf(x, 0.f) + log1pf(expf(-fabsf(x)));
    rank[e] = atomicAdd(&cnt[dst[e]], 1);
}

__global__ void k_scan1(const int* __restrict__ cnt, int* __restrict__ rowptr,
                        int* __restrict__ bsum) {
    __shared__ int s[256];
    int b = blockIdx.x, t = threadIdx.x;
    int i = b * 256 + t;
    int v = (i < N_NODES) ? cnt[i] : 0;
    s[t] = v;
    __syncthreads();
    for (int off = 1; off < 256; off <<= 1) {
        int u = (t >= off) ? s[t - off] : 0;
        __syncthreads();
        s[t] += u;
        __syncthreads();
    }
    if (i < N_NODES) rowptr[i] = s[t] - v;
    if (t == 255) bsum[b] = s[255];
}

__global__ void k_scan2(const int* __restrict__ bsum, int* __restrict__ boff) {
    __shared__ int s[256];
    int t = threadIdx.x;
    int v = (t < NB_SCAN) ? bsum[t] : 0;
    s[t] = v;
    __syncthreads();
    for (int off = 1; off < 256; off <<= 1) {
        int u = (t >= off) ? s[t - off] : 0;
        __syncthreads();
        s[t] += u;
        __syncthreads();
    }
    if (t < NB_SCAN) boff[t] = s[t] - v;
    if (t == 255) boff[NB_SCAN] = s[255];
}

__global__ void k_scan3(int* __restrict__ rowptr, const int* __restrict__ boff) {
    int b = blockIdx.x, t = threadIdx.x;
    int i = b * 256 + t;
    if (i < N_NODES) rowptr[i] += boff[b];
    if (i == 0) rowptr[N_NODES] = boff[NB_SCAN];
}

__global__ void k_fill2(const int* __restrict__ src, const int* __restrict__ dst,
                        const float* __restrict__ ew, const int* __restrict__ rank,
                        const int* __restrict__ rowptr, int2* __restrict__ ecsr) {
    int e = blockIdx.x * blockDim.x + threadIdx.x;
    if (e >= N_EDGES) return;
    int pos = rowptr[dst[e]] + rank[e];
    ecsr[pos] = make_int2(src[e], __float_as_int(ew[e]));
}

__global__ void k_degdinv(const int* __restrict__ rowptr, const int2* __restrict__ ecsr,
                          float* __restrict__ dinv) {
    int n = blockIdx.x * blockDim.x + threadIdx.x;
    if (n >= N_NODES) return;
    int beg = rowptr[n], end = rowptr[n + 1];
    float s = 1.0f;  // self-loop weight
    for (int p = beg; p < end; p++) s += __int_as_float(ecsr[p].y);
    dinv[n] = rsqrtf(s);
}

__global__ void k_norm(const int* __restrict__ rowptr, const float* __restrict__ dinv,
                       int2* __restrict__ ecsr) {
    int n = blockIdx.x * blockDim.x + threadIdx.x;
    if (n >= N_NODES) return;
    int beg = rowptr[n], end = rowptr[n + 1];
    float dn = dinv[n];
    for (int p = beg; p < end; p++) {
        int2 r = ecsr[p];
        float w = dinv[r.x] * __int_as_float(r.y) * dn;
        ecsr[p] = make_int2(r.x, __float_as_int(w));
    }
}

// ---------------------------------------------------------------------------
// Weight prep: W[K,N] f32 -> Wt[N, 2K] fp16 (hi plane 0..K-1, lo plane K..2K-1)
// ---------------------------------------------------------------------------

#define WPREP_TOTAL 131072

__global__ void k_wprep(const float* __restrict__ W1, const float* __restrict__ W2,
                        const float* __restrict__ W3,
                        u16* __restrict__ B1, u16* __restrict__ B2, u16* __restrict__ B3) {
    int idx = blockIdx.x * blockDim.x + threadIdx.x;
    const float* W; u16* B; int K, N, base;
    if (idx < 32768)       { W = W1; B = B1; K = 128; N = 256; base = 0; }
    else if (idx < 98304)  { W = W2; B = B2; K = 256; N = 256; base = 32768; }
    else if (idx < 131072) { W = W3; B = B3; K = 256; N = 128; base = 98304; }
    else return;
    int p = idx - base;
    int n = p % N, k = p / N;
    float x = W[(size_t)k * N + n];
    u16 hi = f2h(x);
    u16 lo = f2h(x - h2f(hi));
    B[(size_t)n * (2 * K) + k] = hi;
    B[(size_t)n * (2 * K) + K + k] = lo;
}

// ---------------------------------------------------------------------------
// Aggregation. INF: 0 = f32 rows, 1 = fp16 rows. OUTM: 0 = f32 (+bias),
// 1 = fp16 [N, D]. One wave per node, 4-deep gather pipeline.
// ---------------------------------------------------------------------------

template <int D, int INF, int OUTM, bool BIAS>
__global__ __launch_bounds__(256) void k_agg(const void* __restrict__ inv,
                                             const int* __restrict__ rowptr,
                                             const int2* __restrict__ ecsr,
                                             const float* __restrict__ dinv,
                                             const float* __restrict__ bias,
                                             void* __restrict__ outv) {
    int node = blockIdx.x * 4 + (threadIdx.x >> 6);
    int lane = threadIdx.x & 63;
    if (node >= N_NODES) return;
    float dn = dinv[node];
    float dd = dn * dn;
    int beg = rowptr[node], end = rowptr[node + 1];

    if (D == 256) {
        const float* inf = (const float*)inv;
        const u16* inh = (const u16*)inv;
        float sx, sy, sz, sw;
        if (INF == 0) {
            float4 sv = *(reinterpret_cast<const float4*>(inf + (size_t)node * D) + lane);
            sx = sv.x; sy = sv.y; sz = sv.z; sw = sv.w;
        } else {
            uint2 raw = *reinterpret_cast<const uint2*>(inh + (size_t)node * D + lane * 4);
            float2 f01 = h2f2(raw.x), f23 = h2f2(raw.y);
            sx = f01.x; sy = f01.y; sz = f23.x; sw = f23.y;
        }
        float ax = dd * sx, ay = dd * sy, az = dd * sz, aw = dd * sw;
        int p = beg;
        for (; p + 4 <= end; p += 4) {
            int2 e0 = ecsr[p], e1 = ecsr[p + 1], e2 = ecsr[p + 2], e3 = ecsr[p + 3];
            float w0 = __int_as_float(e0.y), w1 = __int_as_float(e1.y);
            float w2 = __int_as_float(e2.y), w3 = __int_as_float(e3.y);
            if (INF == 0) {
                float4 r0 = *(reinterpret_cast<const float4*>(inf + (size_t)e0.x * D) + lane);
                float4 r1 = *(reinterpret_cast<const float4*>(inf + (size_t)e1.x * D) + lane);
                float4 r2 = *(reinterpret_cast<const float4*>(inf + (size_t)e2.x * D) + lane);
                float4 r3 = *(reinterpret_cast<const float4*>(inf + (size_t)e3.x * D) + lane);
                ax += w0 * r0.x; ay += w0 * r0.y; az += w0 * r0.z; aw += w0 * r0.w;
                ax += w1 * r1.x; ay += w1 * r1.y; az += w1 * r1.z; aw += w1 * r1.w;
                ax += w2 * r2.x; ay += w2 * r2.y; az += w2 * r2.z; aw += w2 * r2.w;
                ax += w3 * r3.x; ay += w3 * r3.y; az += w3 * r3.z; aw += w3 * r3.w;
            } else {
                uint2 q0 = *reinterpret_cast<const uint2*>(inh + (size_t)e0.x * D + lane * 4);
                uint2 q1 = *reinterpret_cast<const uint2*>(inh + (size_t)e1.x * D + lane * 4);
                uint2 q2 = *reinterpret_cast<const uint2*>(inh + (size_t)e2.x * D + lane * 4);
                uint2 q3 = *reinterpret_cast<const uint2*>(inh + (size_t)e3.x * D + lane * 4);
                float2 a0 = h2f2(q0.x), b0 = h2f2(q0.y);
                float2 a1 = h2f2(q1.x), b1 = h2f2(q1.y);
                float2 a2 = h2f2(q2.x), b2 = h2f2(q2.y);
                float2 a3 = h2f2(q3.x), b3 = h2f2(q3.y);
                ax += w0 * a0.x; ay += w0 * a0.y; az += w0 * b0.x; aw += w0 * b0.y;
                ax += w1 * a1.x; ay += w1 * a1.y; az += w1 * b1.x; aw += w1 * b1.y;
                ax += w2 * a2.x; ay += w2 * a2.y; az += w2 * b2.x; aw += w2 * b2.y;
                ax += w3 * a3.x; ay += w3 * a3.y; az += w3 * b3.x; aw += w3 * b3.y;
            }
        }
        for (; p < end; p++) {
            int2 e0 = ecsr[p];
            float w0 = __int_as_float(e0.y);
            if (INF == 0) {
                float4 r0 = *(reinterpret_cast<const float4*>(inf + (size_t)e0.x * D) + lane);
                ax += w0 * r0.x; ay += w0 * r0.y; az += w0 * r0.z; aw += w0 * r0.w;
            } else {
                uint2 q0 = *reinterpret_cast<const uint2*>(inh + (size_t)e0.x * D + lane * 4);
                float2 a0 = h2f2(q0.x), b0 = h2f2(q0.y);
                ax += w0 * a0.x; ay += w0 * a0.y; az += w0 * b0.x; aw += w0 * b0.y;
            }
        }
        if (OUTM == 0) {
            float* out = (float*)outv;
            if (BIAS) {
                float4 b = *(reinterpret_cast<const float4*>(bias) + lane);
                ax += b.x; ay += b.y; az += b.z; aw += b.w;
            }
            float4 res; res.x = ax; res.y = ay; res.z = az; res.w = aw;
            *(reinterpret_cast<float4*>(out + (size_t)node * D) + lane) = res;
        } else {
            u16* out = (u16*)outv;  // fp16 [N, 256]
            ushort4 hv;
            hv.x = f2h(ax); hv.y = f2h(ay); hv.z = f2h(az); hv.w = f2h(aw);
            *reinterpret_cast<ushort4*>(out + (size_t)node * D + lane * 4) = hv;
        }
    } else {  // D == 128
        const float* inf = (const float*)inv;
        const u16* inh = (const u16*)inv;
        float sx, sy;
        if (INF == 0) {
            float2 sv = *(reinterpret_cast<const float2*>(inf + (size_t)node * D) + lane);
            sx = sv.x; sy = sv.y;
        } else {
            unsigned int raw = *reinterpret_cast<const unsigned int*>(inh + (size_t)node * D + lane * 2);
            float2 f = h2f2(raw);
            sx = f.x; sy = f.y;
        }
        float ax = dd * sx, ay = dd * sy;
        int p = beg;
        for (; p + 4 <= end; p += 4) {
            int2 e0 = ecsr[p], e1 = ecsr[p + 1], e2 = ecsr[p + 2], e3 = ecsr[p + 3];
            float w0 = __int_as_float(e0.y), w1 = __int_as_float(e1.y);
            float w2 = __int_as_float(e2.y), w3 = __int_as_float(e3.y);
            if (INF == 0) {
                float2 r0 = *(reinterpret_cast<const float2*>(inf + (size_t)e0.x * D) + lane);
                float2 r1 = *(reinterpret_cast<const float2*>(inf + (size_t)e1.x * D) + lane);
                float2 r2 = *(reinterpret_cast<const float2*>(inf + (size_t)e2.x * D) + lane);
                float2 r3 = *(reinterpret_cast<const float2*>(inf + (size_t)e3.x * D) + lane);
                ax += w0 * r0.x; ay += w0 * r0.y;
                ax += w1 * r1.x; ay += w1 * r1.y;
                ax += w2 * r2.x; ay += w2 * r2.y;
                ax += w3 * r3.x; ay += w3 * r3.y;
            } else {
                unsigned int q0 = *reinterpret_cast<const unsigned int*>(inh + (size_t)e0.x * D + lane * 2);
                unsigned int q1 = *reinterpret_cast<const unsigned int*>(inh + (size_t)e1.x * D + lane * 2);
                unsigned int q2 = *reinterpret_cast<const unsigned int*>(inh + (size_t)e2.x * D + lane * 2);
                unsigned int q3 = *reinterpret_cast<const unsigned int*>(inh + (size_t)e3.x * D + lane * 2);
                float2 f0 = h2f2(q0), f1 = h2f2(q1), f2 = h2f2(q2), f3 = h2f2(q3);
                ax += w0 * f0.x; ay += w0 * f0.y;
                ax += w1 * f1.x; ay += w1 * f1.y;
                ax += w2 * f2.x; ay += w2 * f2.y;
                ax += w3 * f3.x; ay += w3 * f3.y;
            }
        }
        for (; p < end; p++) {
            int2 e0 = ecsr[p];
            float w0 = __int_as_float(e0.y);
            if (INF == 0) {
                float2 r0 = *(reinterpret_cast<const float2*>(inf + (size_t)e0.x * D) + lane);
                ax += w0 * r0.x; ay += w0 * r0.y;
            } else {
                unsigned int q0 = *reinterpret_cast<const unsigned int*>(inh + (size_t)e0.x * D + lane * 2);
                float2 f0 = h2f2(q0);
                ax += w0 * f0.x; ay += w0 * f0.y;
            }
        }
        if (OUTM == 0) {
            float* out = (float*)outv;
            if (BIAS) {
                float2 b = *(reinterpret_cast<const float2*>(bias) + lane);
                ax += b.x; ay += b.y;
            }
            float2 res; res.x = ax; res.y = ay;
            *(reinterpret_cast<float2*>(out + (size_t)node * D) + lane) = res;
        } else {
            u16* out = (u16*)outv;  // fp16 [N, 128]
            ushort2 hv; hv.x = f2h(ax); hv.y = f2h(ay);
            *reinterpret_cast<ushort2*>(out + (size_t)node * D + lane * 2) = hv;
        }
    }
}

// ---------------------------------------------------------------------------
// fp16 MFMA GEMM with fp16-hilo weights (unchanged from R8).
// ---------------------------------------------------------------------------

template <int OUT, bool BIAS, bool RELU>
__global__ __launch_bounds__(256) void k_gemm_h(const u16* __restrict__ Ap,
                                                const u16* __restrict__ Bp,
                                                const float* __restrict__ bias,
                                                void* __restrict__ Cv,
                                                int M, int K, int NN) {
    const int KP2 = 2 * K;
    __shared__ u16 As[8 * 544];
    __shared__ u16 Bs[2 * 8 * 544];
    int tid = threadIdx.x;
    int bm = blockIdx.y * 128;
    int bn = blockIdx.x * 128;
    int l = tid & 63;
    int w = tid >> 6;
    int wr = w >> 1, wc = w & 1;

    f32x4 zero = {0.f, 0.f, 0.f, 0.f};
    f32x4 acc[4][4];
    #pragma unroll
    for (int i = 0; i < 4; i++)
        #pragma unroll
        for (int j = 0; j < 4; j++) acc[i][j] = zero;

    for (int k0 = 0; k0 < K; k0 += 32) {
        #pragma unroll
        for (int q = 0; q < 2; q++) {
            int idx = tid + q * 256;
            int r = idx >> 2, o = idx & 3;
            int gr = bm + r;
            uint4 va = make_uint4(0u, 0u, 0u, 0u);
            if (gr < M)
                va = *reinterpret_cast<const uint4*>(Ap + (size_t)gr * K + k0 + o * 8);
            *reinterpret_cast<uint4*>(&As[(r >> 4) * 544 + o * 136 + (r & 15) * 8]) = va;
        }
        #pragma unroll
        for (int q = 0; q < 4; q++) {
            int idx = tid + q * 256;
            int r = idx >> 3, oct = idx & 7;
            int hf = oct >> 2, o = oct & 3;
            uint4 vb = *reinterpret_cast<const uint4*>(
                Bp + (size_t)(bn + r) * KP2 + hf * K + k0 + o * 8);
            *reinterpret_cast<uint4*>(
                &Bs[hf * 4352 + (r >> 4) * 544 + o * 136 + (r & 15) * 8]) = vb;
        }
        __syncthreads();
        int fro = (l >> 4) * 136 + (l & 15) * 8;
        f16x8 a[4], bh[4], bl[4];
        #pragma unroll
        for (int i = 0; i < 4; i++)
            a[i] = *reinterpret_cast<const f16x8*>(&As[(wr * 4 + i) * 544 + fro]);
        #pragma unroll
        for (int j = 0; j < 4; j++) {
            bh[j] = *reinterpret_cast<const f16x8*>(&Bs[(wc * 4 + j) * 544 + fro]);
            bl[j] = *reinterpret_cast<const f16x8*>(&Bs[4352 + (wc * 4 + j) * 544 + fro]);
        }
        #pragma unroll
        for (int i = 0; i < 4; i++)
            #pragma unroll
            for (int j = 0; j < 4; j++) {
                acc[i][j] = __builtin_amdgcn_mfma_f32_16x16x32_f16(a[i], bh[j], acc[i][j], 0, 0, 0);
                acc[i][j] = __builtin_amdgcn_mfma_f32_16x16x32_f16(a[i], bl[j], acc[i][j], 0, 0, 0);
            }
        __syncthreads();
    }

    int cl = l & 15;
    int rq = (l >> 4) * 4;
    float bv[4];
    #pragma unroll
    for (int j = 0; j < 4; j++) {
        int gc = bn + wc * 64 + j * 16 + cl;
        bv[j] = BIAS ? bias[gc] : 0.f;
    }
    #pragma unroll
    for (int i = 0; i < 4; i++) {
        #pragma unroll
        for (int r = 0; r < 4; r++) {
            int grow = bm + wr * 64 + i * 16 + rq + r;
            if (grow >= M) continue;
            #pragma unroll
            for (int j = 0; j < 4; j++) {
                int gc = bn + wc * 64 + j * 16 + cl;
                float v = acc[i][j][r];
                if (BIAS) v += bv[j];
                if (RELU) v = fmaxf(v, 0.f);
                if (OUT == 0) {
                    ((float*)Cv)[(size_t)grow * NN + gc] = v;
                } else {
                    ((u16*)Cv)[(size_t)grow * NN + gc] = f2h(v);
                }
            }
        }
    }
}

// ---------------------------------------------------------------------------
// launch
// ---------------------------------------------------------------------------

extern "C" void kernel_launch(void* const* d_in, const int* in_sizes, int n_in,
                              void* d_out, int out_size, void* d_ws, size_t ws_size,
                              hipStream_t stream) {
    const float* x   = (const float*)d_in[0];
    const int*   ei  = (const int*)d_in[1];
    const float* wts = (const float*)d_in[2];
    const float* W1  = (const float*)d_in[3];
    const float* b1  = (const float*)d_in[4];
    const float* W2  = (const float*)d_in[5];
    const float* b2  = (const float*)d_in[6];
    const float* W3  = (const float*)d_in[7];
    const float* b3  = (const float*)d_in[8];
    float* out = (float*)d_out;
    const int* src = ei;
    const int* dst = ei + N_EDGES;

    float* bufA   = (float*)d_ws;                         // fp16 [N,256] max
    float* bufB   = bufA + (size_t)N_NODES * D_HID;       // fp16 [N,256] max
    float* ew     = bufB + (size_t)N_NODES * D_HID;       // [E]
    float* dinv   = ew + N_EDGES;                         // [N]
    int*   cnt    = (int*)(dinv + N_NODES);               // [N]
    int*   rank   = cnt + N_NODES;                        // [E]
    int*   rowptr = rank + N_EDGES;                       // [N+1]
    int2*  ecsr   = (int2*)(rowptr + (N_NODES + 2));      // [E] packed {src, w}
    u16*   Wb1    = (u16*)(ecsr + N_EDGES);               // [256*256]
    u16*   Wb2    = Wb1 + 256 * 256;                      // [256*512]
    u16*   Wb3    = Wb2 + 256 * 512;                      // [128*512]
    int*   bsum   = (int*)(Wb3 + 128 * 512);              // [NB_SCAN]
    int*   boff   = bsum + NB_SCAN;                       // [NB_SCAN+1]

    hipMemsetAsync(cnt, 0, sizeof(int) * N_NODES, stream);

    int ethreads = 256;
    int eblocks = (N_EDGES + ethreads - 1) / ethreads;
    int nblocks = (N_NODES + 255) / 256;
    k_hist<<<eblocks, ethreads, 0, stream>>>(dst, wts, ew, rank, cnt);
    k_scan1<<<NB_SCAN, 256, 0, stream>>>(cnt, rowptr, bsum);
    k_scan2<<<1, 256, 0, stream>>>(bsum, boff);
    k_scan3<<<NB_SCAN, 256, 0, stream>>>(rowptr, boff);
    k_fill2<<<eblocks, ethreads, 0, stream>>>(src, dst, ew, rank, rowptr, ecsr);
    k_degdinv<<<nblocks, 256, 0, stream>>>(rowptr, ecsr, dinv);
    k_norm<<<nblocks, 256, 0, stream>>>(rowptr, dinv, ecsr);
    k_wprep<<<(WPREP_TOTAL + 255) / 256, 256, 0, stream>>>(W1, W2, W3, Wb1, Wb2, Wb3);

    int aggBlocks = (N_NODES + 3) / 4;
    int gy = (N_NODES + 127) / 128;  // 391

    // agg1: x (f32) -> bufA fp16 [N,128]
    k_agg<128, 0, 1, false><<<aggBlocks, 256, 0, stream>>>(x, rowptr, ecsr, dinv, nullptr, bufA);
    // gemm1: h1 = relu(bufA @ W1 + b1) -> bufB fp16 [N,256]
    {
        dim3 g(2, gy);
        k_gemm_h<1, true, true><<<g, 256, 0, stream>>>((const u16*)bufA, Wb1, b1, bufB,
                                                       N_NODES, D_IN, D_HID);
    }
    // agg2: bufB fp16 -> bufA fp16 [N,256]
    k_agg<256, 1, 1, false><<<aggBlocks, 256, 0, stream>>>(bufB, rowptr, ecsr, dinv, nullptr, bufA);
    // gemm2: h2 = relu(bufA @ W2 + b2) -> bufB fp16 [N,256]
    {
        dim3 g(2, gy);
        k_gemm_h<1, true, true><<<g, 256, 0, stream>>>((const u16*)bufA, Wb2, b2, bufB,
                                                       N_NODES, D_HID, D_HID);
    }
    // gemm3: y3 = bufB @ W3 -> bufA fp16 [N,128]
    {
        dim3 g(1, gy);
        k_gemm_h<1, false, false><<<g, 256, 0, stream>>>((const u16*)bufB, Wb3, nullptr, bufA,
                                                         N_NODES, D_HID, D_OUT);
    }
    // agg3: bufA fp16 -> out f32 + b3
    k_agg<128, 1, 0, true><<<aggBlocks, 256, 0, stream>>>(bufA, rowptr, ecsr, dinv, b3, out);
}